// Round 12
// baseline (73285.370 us; speedup 1.0000x reference)
//
#include <hip/hip_runtime.h>
#include <math.h>

#define NWG 256
#define NTH 512
#define MASTER 255

typedef _Float16 f16;
typedef __attribute__((ext_vector_type(8))) _Float16 h8;
typedef __attribute__((ext_vector_type(4))) float f4;

namespace {
constexpr int T_ = 1024, F_ = 160, H_ = 1024;
constexpr float SC = 2048.f;
constexpr float INV = 1.f / 2048.f;

// state geometry (in halfs). layout: [oct][batch 64][8], hi octs then lo octs
constexpr int ESLOTH = 512 * 64 * 8;   // encoder slot: 256 hi + 256 lo octs (512 KB)
constexpr int DSLOTH = 256 * 64 * 8;   // decoder slot: 128 hi + 128 lo octs (256 KB)
constexpr int ELO = 256;               // lo oct offset (encoder)
constexpr int DLO = 128;               // lo oct offset (decoder)

// bar region dword map (49152 B total, memset each launch):
//   gbar flags: wg*32 (0..8160) | gen: 8192
//   xflag(myx,slot): 8704 + myx*256 + slot*8 | xgen: 10752 + myx*32
//   claim: 11264 + myx*16 | init: 11520
constexpr size_t WS_BAR  = 0;                                    // 49152 B
constexpr size_t WS_CVEC = 49152;                                // 3H f32
constexpr size_t WS_WDEC = WS_CVEC + 12288;                      // 4H*H f32
constexpr size_t WS_ENCA = WS_WDEC + (size_t)4 * H_ * H_ * 4;    // 2 slots
constexpr size_t WS_DECA = WS_ENCA + (size_t)2 * ESLOTH * 2;
constexpr size_t WS_STRM = WS_DECA + (size_t)2 * DSLOTH * 2;
constexpr size_t WS_STG  = WS_STRM + (size_t)8388608 * 2;        // 8 XCD x 512 KB
constexpr size_t WS_NEED = WS_STG + (size_t)8 * 524288;

// LDS byte offsets (fixed across roles)
constexpr int DBUF_B = 135168;           // f32[2][32][68]
constexpr int TBUF_B = DBUF_B + 17408;   // f32[8][64]
constexpr int ZP_B   = TBUF_B + 2048;    // 16 halfs of zeros
constexpr int LDS_B  = ZP_B + 64;
}

__device__ __forceinline__ f4 MF(h8 a, h8 b, f4 c) {
  return __builtin_amdgcn_mfma_f32_16x16x32_f16(a, b, c, 0, 0, 0);
}

// split v into fp16 hi (0 if would be denormal) + fp16 lo' scaled by 2048
__device__ __forceinline__ void fsplit(float v, f16& hi, f16& lo) {
  const float hf = (fabsf(v) >= 6.103515625e-05f) ? (float)(f16)v : 0.f;
  hi = (f16)hf;
  lo = (f16)((v - hf) * SC);
}

// ---- grid barrier: flag-array + master scan (R11, proven). ----
__device__ __forceinline__ void gbar(unsigned* bar, int wg, unsigned& phase) {
  __syncthreads();
  ++phase;
  const int tid = threadIdx.x;
  unsigned* gen = bar + 8192;
  if (wg == MASTER) {
    if (tid == 0)
      __hip_atomic_store(&bar[MASTER * 32], phase, __ATOMIC_RELEASE, __HIP_MEMORY_SCOPE_AGENT);
    if (tid < 256) {
      while (__hip_atomic_load(&bar[tid * 32], __ATOMIC_RELAXED, __HIP_MEMORY_SCOPE_AGENT) < phase)
        __builtin_amdgcn_s_sleep(1);
    }
    __syncthreads();
    if (tid == 0) {
      __hip_atomic_store(gen, phase, __ATOMIC_RELEASE, __HIP_MEMORY_SCOPE_AGENT);
      (void)__hip_atomic_load(gen, __ATOMIC_ACQUIRE, __HIP_MEMORY_SCOPE_AGENT);
    }
  } else {
    if (tid == 0) {
      __hip_atomic_store(&bar[wg * 32], phase, __ATOMIC_RELEASE, __HIP_MEMORY_SCOPE_AGENT);
      while (__hip_atomic_load(gen, __ATOMIC_RELAXED, __HIP_MEMORY_SCOPE_AGENT) < phase)
        __builtin_amdgcn_s_sleep(1);
      (void)__hip_atomic_load(gen, __ATOMIC_ACQUIRE, __HIP_MEMORY_SCOPE_AGENT);
    }
  }
  __syncthreads();
}

// ---- intra-XCD barrier: flag-store + leader (slot 0) scan, no RMWs. ----
__device__ __forceinline__ void lbar(unsigned* bar, unsigned& lphase, int myx, int slot) {
  __syncthreads();
  ++lphase;
  const int tid = threadIdx.x;
  unsigned* xgen = bar + 10752 + myx * 32;
  if (slot == 0) {
    if (tid >= 1 && tid < 32) {
      while (__hip_atomic_load(&bar[8704 + myx * 256 + tid * 8], __ATOMIC_RELAXED, __HIP_MEMORY_SCOPE_AGENT) < lphase)
        __builtin_amdgcn_s_sleep(1);
    }
    __syncthreads();
    if (tid == 0) {
      __hip_atomic_store(xgen, lphase, __ATOMIC_RELEASE, __HIP_MEMORY_SCOPE_AGENT);
      (void)__hip_atomic_load(xgen, __ATOMIC_ACQUIRE, __HIP_MEMORY_SCOPE_AGENT);
    }
  } else {
    if (tid == 0) {
      __hip_atomic_store(&bar[8704 + myx * 256 + slot * 8], lphase, __ATOMIC_RELEASE, __HIP_MEMORY_SCOPE_AGENT);
      while (__hip_atomic_load(xgen, __ATOMIC_RELAXED, __HIP_MEMORY_SCOPE_AGENT) < lphase)
        __builtin_amdgcn_s_sleep(1);
      (void)__hip_atomic_load(xgen, __ATOMIC_ACQUIRE, __HIP_MEMORY_SCOPE_AGENT);
    }
  }
  __syncthreads();
}

// ---- LLC -> XCD-private staging (plain loads + plain stores -> dirty local L2).
// encoder: h0 octs (bit7=0) parity (s-1)&1 ; h1 octs (bit7=1) parity s&1.
__device__ __forceinline__ void enc_copy(const f16* encA, f16* stgX, int s, int slot, int tid) {
  const int oct = slot * 16 + (tid >> 5);
  const int l32 = tid & 31;
  const size_t par = (size_t)((((oct & 128) ? s : (s - 1)) & 1)) * ESLOTH;
  const f16* src = encA + par + (size_t)oct * 512 + l32 * 16;
  f16* dst = stgX + (size_t)oct * 512 + l32 * 16;
  const h8 a = *(const h8*)src;
  const h8 b = *(const h8*)(src + 8);
  *(h8*)dst = a;
  *(h8*)(dst + 8) = b;
}
// decoder: octs 0..255 from parity (t-1)&1
__device__ __forceinline__ void dec_copy(const f16* decA, f16* stgX, int t, int slot, int tid) {
  const int oct = slot * 8 + (tid >> 6);
  const int l64 = tid & 63;
  const f16* src = decA + (size_t)((t - 1) & 1) * DSLOTH + (size_t)oct * 512 + l64 * 8;
  f16* dst = stgX + (size_t)oct * 512 + l64 * 8;
  *(h8*)dst = *(const h8*)src;
}

// ---- staging: f32 weights -> fp16 hi/lo pairs in LDS ----
__device__ void stageEnc(f16* __restrict__ whi, f16* __restrict__ wlo,
                         const float* __restrict__ Wx, const float* __restrict__ Wh,
                         int KX, int XOo, int KO, int u0, int tid) {
  for (int task = tid; task < KO * 24; task += NTH) {
    const int oct = task / 24;
    const int sl = task - oct * 24;
    const int g = (sl < 16) ? (sl >> 3) : 2;
    const int u = u0 + (sl & 7);
    const float* src = (oct < XOo)
        ? (Wx + (size_t)(g * H_ + u) * KX + (size_t)oct * 8)
        : (Wh + (size_t)(g * H_ + u) * H_ + (size_t)(oct - XOo) * 8);
    const float4 a = *(const float4*)src;
    const float4 b = *(const float4*)(src + 4);
    const float v[8] = {a.x, a.y, a.z, a.w, b.x, b.y, b.z, b.w};
    h8 hv, lv;
#pragma unroll
    for (int e = 0; e < 8; ++e) { f16 hh, ll; fsplit(v[e], hh, ll); hv[e] = hh; lv[e] = ll; }
    *(h8*)(whi + ((size_t)oct * 25 + sl) * 8) = hv;
    if (wlo) *(h8*)(wlo + ((size_t)oct * 25 + sl) * 8) = lv;
  }
}

// decoder 32-slot rows (pad 33): slots g*8+j, g in {r,z,ni,nh}, full K
__device__ void stageDec(f16* __restrict__ whi, f16* __restrict__ wlo,
                         const float* __restrict__ wdec, const float* __restrict__ dWhh,
                         int u0, int tid, bool t1set) {
  for (int task = tid; task < 128 * 32; task += NTH) {
    const int oct = task >> 5, sl = task & 31;
    const int g = sl >> 3;
    const int u = u0 + (sl & 7);
    float v[8];
    if (t1set) {
      if (g == 2) {
#pragma unroll
        for (int e = 0; e < 8; ++e) v[e] = 0.f;
      } else {
        const float* s = dWhh + (size_t)((g == 3 ? 2 : g) * H_ + u) * H_ + (size_t)oct * 8;
        const float4 a = *(const float4*)s, b = *(const float4*)(s + 4);
        v[0]=a.x; v[1]=a.y; v[2]=a.z; v[3]=a.w; v[4]=b.x; v[5]=b.y; v[6]=b.z; v[7]=b.w;
      }
    } else {
      const float* s = wdec + (size_t)(g * H_ + u) * H_ + (size_t)oct * 8;
      const float4 a = *(const float4*)s, b = *(const float4*)(s + 4);
      v[0]=a.x; v[1]=a.y; v[2]=a.z; v[3]=a.w; v[4]=b.x; v[5]=b.y; v[6]=b.z; v[7]=b.w;
    }
    h8 hv, lv;
#pragma unroll
    for (int e = 0; e < 8; ++e) { f16 hh, ll; fsplit(v[e], hh, ll); hv[e] = hh; lv[e] = ll; }
    *(h8*)(whi + ((size_t)oct * 33 + sl) * 8) = hv;
    *(h8*)(wlo + ((size_t)oct * 33 + sl) * 8) = lv;
  }
}

__device__ void stageProj(f16* __restrict__ whi, f16* __restrict__ wlo,
                          const float* __restrict__ pW, int f0, int tid) {
  for (int task = tid; task < 128 * 16; task += NTH) {
    const int oct = task >> 4, sl = task & 15;
    const float* s = pW + (size_t)(f0 + sl) * H_ + (size_t)oct * 8;
    const float4 a = *(const float4*)s, b = *(const float4*)(s + 4);
    const float v[8] = {a.x, a.y, a.z, a.w, b.x, b.y, b.z, b.w};
    h8 hv, lv;
#pragma unroll
    for (int e = 0; e < 8; ++e) { f16 hh, ll; fsplit(v[e], hh, ll); hv[e] = hh; lv[e] = ll; }
    *(h8*)(whi + ((size_t)oct * 17 + sl) * 8) = hv;
    *(h8*)(wlo + ((size_t)oct * 17 + sl) * 8) = lv;
  }
}

// ---- MFMA k-phase: A (hi+lo pairs) from global (staging or state), Whi from
// LDS, Wlo from LDS or stream.  1-deep pipeline (locality-safe, R8/R9/R10). ----
template<int NT, bool NSPLIT, int ROWH, bool STRM>
__device__ __forceinline__ void gmm(f4* Dh, f4* Dc,
    const f16* __restrict__ Ab, int aoctBase, int loOct,
    const f16* __restrict__ whi, const f16* __restrict__ wlo,
    const f16* __restrict__ strm,
    int ktn, int octBase, int XO, int ls, int lq, int lane,
    const f16* __restrict__ zp) {
  auto LD = [&](int kk, h8& ah, h8& al, h8& bh0, h8& bl0, h8& bh1, h8& bl1) {
    const int aoct = aoctBase + kk * 4 + lq;
    ah = *(const h8*)(Ab + (size_t)aoct * 512);
    al = *(const h8*)(Ab + (size_t)(aoct + loOct) * 512);
    const int oct = octBase + kk * 4 + lq;
    bh0 = *(const h8*)(whi + ((size_t)oct * ROWH + ls) * 8);
    if constexpr (STRM) bl0 = *(const h8*)(strm + ((size_t)(kk * 2) * 64 + lane) * 8);
    else bl0 = *(const h8*)(wlo + ((size_t)oct * ROWH + ls) * 8);
    if constexpr (NT == 2) {
      bool act = true; int psl;
      if constexpr (NSPLIT) { act = (ls < 8) ? (oct < XO) : (oct >= XO); psl = 16 + (ls & 7); }
      else { psl = 16 + ls; }
      bh1 = *(const h8*)(act ? (whi + ((size_t)oct * ROWH + psl) * 8) : zp);
      if constexpr (STRM) bl1 = *(const h8*)(strm + ((size_t)(kk * 2 + 1) * 64 + lane) * 8);
      else bl1 = *(const h8*)(act ? (wlo + ((size_t)oct * ROWH + psl) * 8) : zp);
    }
  };
  h8 ah, al, bh0, bl0, bh1, bl1;
  LD(0, ah, al, bh0, bl0, bh1, bl1);
  for (int kk = 0; kk < ktn; ++kk) {
    h8 ah2, al2, bh02, bl02, bh12, bl12;
    const int nk = (kk + 1 < ktn) ? (kk + 1) : kk;
    LD(nk, ah2, al2, bh02, bl02, bh12, bl12);
    Dh[0] = MF(ah, bh0, Dh[0]);
    Dc[0] = MF(al, bh0, Dc[0]);
    Dc[0] = MF(ah, bl0, Dc[0]);
    if constexpr (NT == 2) {
      Dh[1] = MF(ah, bh1, Dh[1]);
      Dc[1] = MF(al, bh1, Dc[1]);
      Dc[1] = MF(ah, bl1, Dc[1]);
    }
    ah = ah2; al = al2; bh0 = bh02; bl0 = bl02;
    if constexpr (NT == 2) { bh1 = bh12; bl1 = bl12; }
  }
}

// encoder L0 x-part: f32 x -> in-register hi/lo, W octs 0..19 (ni active, nh inactive)
__device__ __forceinline__ void gmm_x(f4* Dh, f4* Dc, const float* __restrict__ xp,
    const f16* __restrict__ whi, const f16* __restrict__ wlo,
    int ls, int lq, const f16* __restrict__ zp) {
#pragma unroll
  for (int kk = 0; kk < 5; ++kk) {
    const float4 a = *(const float4*)(xp + kk * 32);
    const float4 b = *(const float4*)(xp + kk * 32 + 4);
    const float v[8] = {a.x, a.y, a.z, a.w, b.x, b.y, b.z, b.w};
    h8 ah, al;
#pragma unroll
    for (int e = 0; e < 8; ++e) { f16 hh, ll; fsplit(v[e], hh, ll); ah[e] = hh; al[e] = ll; }
    const int oct = kk * 4 + lq;
    {
      const h8 bh2 = *(const h8*)(whi + ((size_t)oct * 25 + ls) * 8);
      const h8 bl2 = *(const h8*)(wlo + ((size_t)oct * 25 + ls) * 8);
      Dh[0] = MF(ah, bh2, Dh[0]);
      Dc[0] = MF(al, bh2, Dc[0]);
      Dc[0] = MF(ah, bl2, Dc[0]);
    }
    {
      const bool act = (ls < 8);
      const int psl = 16 + (ls & 7);
      const h8 bh2 = *(const h8*)(act ? (whi + ((size_t)oct * 25 + psl) * 8) : zp);
      const h8 bl2 = *(const h8*)(act ? (wlo + ((size_t)oct * 25 + psl) * 8) : zp);
      Dh[1] = MF(ah, bh2, Dh[1]);
      Dc[1] = MF(al, bh2, Dc[1]);
      Dc[1] = MF(ah, bl2, Dc[1]);
    }
  }
}

// ---- setup kernels ----
__global__ void build_c_kernel(const float* __restrict__ dWih, const float* __restrict__ dbih,
                               const float* __restrict__ pb, float* __restrict__ cvec) {
  const int r = blockIdx.x * 256 + threadIdx.x;
  if (r >= 3 * H_) return;
  float a = dbih[r];
  for (int f = 0; f < F_; ++f) a += dWih[(size_t)r * F_ + f] * pb[f];
  cvec[r] = a;
}

__global__ void build_wdec_kernel(const float* __restrict__ dWih, const float* __restrict__ dWhh,
                                  const float* __restrict__ pW, float* __restrict__ wdec) {
  const int idx = blockIdx.x * 256 + threadIdx.x;
  if (idx >= 3 * H_ * 128) return;
  const int row = idx >> 7;
  const int oct = idx & 127;
  float v[8] = {0, 0, 0, 0, 0, 0, 0, 0};
  const float* wr = dWih + (size_t)row * F_;
  for (int f = 0; f < F_; ++f) {
    const float w = wr[f];
    const float4 p0 = *(const float4*)(pW + (size_t)f * H_ + oct * 8);
    const float4 p1 = *(const float4*)(pW + (size_t)f * H_ + oct * 8 + 4);
    v[0] += w * p0.x; v[1] += w * p0.y; v[2] += w * p0.z; v[3] += w * p0.w;
    v[4] += w * p1.x; v[5] += w * p1.y; v[6] += w * p1.z; v[7] += w * p1.w;
  }
  if ((row >> 10) < 2) {
    const float* hr = dWhh + (size_t)row * H_ + oct * 8;
#pragma unroll
    for (int e = 0; e < 8; ++e) v[e] += hr[e];
  }
  float* o = wdec + (size_t)row * H_ + oct * 8;
#pragma unroll
  for (int e = 0; e < 8; ++e) o[e] = v[e];
}
__global__ void build_wdec_nh(const float* __restrict__ dWhh, float* __restrict__ wdec) {
  const int idx = blockIdx.x * 256 + threadIdx.x;
  if (idx >= H_ * H_) return;
  wdec[(size_t)3 * H_ * H_ + idx] = dWhh[(size_t)2 * H_ * H_ + idx];
}

// L1 lo-fragment stream, fragment-ordered: [(wg*2+kb)*32768 + ((kk*2+nt)*64+lane)*8 + j]
__global__ void build_strm(const float* __restrict__ Wih1, const float* __restrict__ Whh1,
                           f16* __restrict__ strm) {
  const size_t idx = (size_t)blockIdx.x * 256 + threadIdx.x;  // 8388608 total
  const int j = (int)(idx & 7);
  const int lane = (int)((idx >> 3) & 63);
  const int nt = (int)((idx >> 9) & 1);
  const int kk = (int)((idx >> 10) & 31);
  const int kb = (int)((idx >> 15) & 1);
  const int wg = (int)(idx >> 16);
  const int c = lane & 15, lq = lane >> 4;
  const int oct = kb * 128 + kk * 4 + lq;
  const int k = oct * 8 + j;
  float v = 0.f;
  if (nt == 0) {
    const int row = (c >> 3) * H_ + wg * 8 + (c & 7);
    v = (oct < 128) ? Wih1[(size_t)row * H_ + k] : Whh1[(size_t)row * H_ + (k - 1024)];
  } else {
    const bool act = (c < 8) ? (oct < 128) : (oct >= 128);
    if (act) {
      const int row = 2 * H_ + wg * 8 + (c & 7);
      v = (oct < 128) ? Wih1[(size_t)row * H_ + k] : Whh1[(size_t)row * H_ + (k - 1024)];
    }
  }
  f16 hh, ll; fsplit(v, hh, ll);
  strm[idx] = ll;
}

// ---- persistent kernel ----
__global__ void __launch_bounds__(NTH, 1) speech_ae_persistent(
    const float* __restrict__ x,
    const float* __restrict__ Wih0, const float* __restrict__ Whh0,
    const float* __restrict__ bih0, const float* __restrict__ bhh0,
    const float* __restrict__ Wih1, const float* __restrict__ Whh1,
    const float* __restrict__ bih1, const float* __restrict__ bhh1,
    const float* __restrict__ fcW, const float* __restrict__ fcb,
    const float* __restrict__ dbih, const float* __restrict__ dbhh,
    const float* __restrict__ pW, const float* __restrict__ pb,
    const float* __restrict__ dWhh,
    float* __restrict__ out, void* ws, int stgok) {
  extern __shared__ char ldsb[];
  __shared__ int bc[3];          // {myxcd, slot, okv}
  f16* wh = (f16*)ldsb;
  float* dbuf = (float*)(ldsb + DBUF_B);
  float* tbuf = (float*)(ldsb + TBUF_B);
  f16* zp = (f16*)(ldsb + ZP_B);

  char* wsb = (char*)ws;
  unsigned* bar = (unsigned*)(wsb + WS_BAR);
  const float* cvec = (const float*)(wsb + WS_CVEC);
  const float* wdec = (const float*)(wsb + WS_WDEC);
  f16* encA = (f16*)(wsb + WS_ENCA);
  f16* decA = (f16*)(wsb + WS_DECA);
  const f16* strm = (const f16*)(wsb + WS_STRM);

  const int tid = threadIdx.x, wg = blockIdx.x;
  const int lane = tid & 63, wv = tid >> 6;
  const int ls = lane & 15, lq = lane >> 4;
  const int m0 = (wv & 3) * 16, kb = wv >> 2;
  const int mb = m0 + ls;
  const bool isL1 = (wg < 128);
  unsigned phase = 0, lphase = 0;
  const f16* strmW = strm + (size_t)(wg * 2 + kb) * 32768;

  // ---- XCD discovery + slot claim (tid 0) ----
  if (tid == 0) {
    const unsigned myx = __builtin_amdgcn_s_getreg((31 << 11) | (0 << 6) | 20) & 15u;
    const unsigned slot = __hip_atomic_fetch_add(&bar[11264 + myx * 16], 1u,
                              __ATOMIC_RELAXED, __HIP_MEMORY_SCOPE_AGENT);
    __hip_atomic_fetch_add(&bar[11520], 1u, __ATOMIC_ACQ_REL, __HIP_MEMORY_SCOPE_AGENT);
    while (__hip_atomic_load(&bar[11520], __ATOMIC_RELAXED, __HIP_MEMORY_SCOPE_AGENT) < (unsigned)NWG)
      __builtin_amdgcn_s_sleep(8);
    (void)__hip_atomic_load(&bar[11520], __ATOMIC_ACQUIRE, __HIP_MEMORY_SCOPE_AGENT);
    int okv = 1, groups = 0; unsigned total = 0;
    for (int xx = 0; xx < 16; ++xx) {
      const unsigned c = __hip_atomic_load(&bar[11264 + xx * 16], __ATOMIC_RELAXED, __HIP_MEMORY_SCOPE_AGENT);
      if (c != 0) { ++groups; if (c != 32u) okv = 0; }
      total += c;
    }
    if (groups != 8 || total != (unsigned)NWG || slot >= 32u) okv = 0;
    bc[0] = (int)myx; bc[1] = (int)slot; bc[2] = okv && stgok;
  }

  // encoder biases (8 units/WG; thread's unit = wv)
  const float* bi = isL1 ? bih1 : bih0;
  const float* bh_ = isL1 ? bhh1 : bhh0;
  const int eru = (isL1 ? wg * 8 : (wg - 128) * 8) + wv;
  const float ebr = bi[eru] + bh_[eru];
  const float ebz = bi[H_ + eru] + bh_[H_ + eru];
  const float ebni = bi[2 * H_ + eru];
  const float ebnh = bh_[2 * H_ + eru];
  float hreg = 0.f;

  // decoder biases
  float b1r = 0, b1z = 0, b1ni = 0, b1nh = 0, bfr = 0, bfz = 0, bfni = 0, bfnh = 0, hdreg = 0.f;
  if (wg < 128) {
    const int rw = wg * 8 + wv;
    b1r = dbih[rw] + dbhh[rw];
    b1z = dbih[H_ + rw] + dbhh[H_ + rw];
    b1ni = dbih[2 * H_ + rw];
    b1nh = dbhh[2 * H_ + rw];
    bfr = cvec[rw] + dbhh[rw];
    bfz = cvec[H_ + rw] + dbhh[H_ + rw];
    bfni = cvec[2 * H_ + rw];
    bfnh = dbhh[2 * H_ + rw];
  }
  const int f0 = (wg - 128) * 16;
  float pbr[4] = {0, 0, 0, 0};
  if (wg >= 128 && wg < 138 && tid < 256) {
    const int fq = tid & 3;
#pragma unroll
    for (int e = 0; e < 4; ++e) pbr[e] = pb[f0 + fq * 4 + e];
  }

  // stage encoder weights
  if (isL1) stageEnc(wh, nullptr, Wih1, Whh1, H_, 128, 256, wg * 8, tid);
  else stageEnc(wh, wh + 29600, Wih0, Whh0, F_, 20, 148, (wg - 128) * 8, tid);
  if (tid < 16) zp[tid] = (f16)0.f;
  __syncthreads();

  const int myx = bc[0], slotId = bc[1], okf = bc[2];
  f16* stgX = (f16*)(wsb + WS_STG) + (size_t)myx * 262144;

  // ============ encoder: L0 (wg>=128) at t=s, L1 (wg<128) at t=s-1 ============
  for (int s = 0; s <= T_; ++s) {
    if (okf && s >= 1) { enc_copy(encA, stgX, s, slotId, tid); lbar(bar, lphase, myx, slotId); }
    const bool active = isL1 ? (s >= 1) : (s < T_);
    if (active) {
      const int t = isL1 ? (s - 1) : s;
      f4 Dh[2] = {{0.f,0.f,0.f,0.f},{0.f,0.f,0.f,0.f}};
      f4 Dc[2] = {{0.f,0.f,0.f,0.f},{0.f,0.f,0.f,0.f}};
      if (isL1) {
        if (kb == 0) {        // h0_t, W octs 0..127
          const f16* Ab = okf ? (stgX + (size_t)mb * 8)
                              : (encA + (size_t)(t & 1) * ESLOTH + (size_t)mb * 8);
          gmm<2, true, 25, true>(Dh, Dc, Ab, 0, ELO, wh, nullptr, strmW, 32, 0, 128, ls, lq, lane, zp);
        } else if (t >= 1) {  // h1_{t-1}, W octs 128..255
          const f16* Ab = okf ? (stgX + (size_t)mb * 8)
                              : (encA + (size_t)((t - 1) & 1) * ESLOTH + (size_t)mb * 8);
          gmm<2, true, 25, true>(Dh, Dc, Ab, 128, ELO, wh, nullptr, strmW, 32, 128, 128, ls, lq, lane, zp);
        }
      } else {
        const f16* Ab = okf ? (stgX + (size_t)mb * 8)
                            : (encA + (size_t)((s - 1) & 1) * ESLOTH + (size_t)mb * 8);
        if (kb == 0) {
          const float* xp = x + ((size_t)mb * T_ + t) * F_ + lq * 8;
          gmm_x(Dh, Dc, xp, wh, wh + 29600, ls, lq, zp);
          if (t >= 1)
            gmm<2, true, 25, false>(Dh, Dc, Ab, 0, ELO, wh, wh + 29600, nullptr, 14, 20, 20, ls, lq, lane, zp);
        } else if (t >= 1) {
          gmm<2, true, 25, false>(Dh, Dc, Ab, 56, ELO, wh, wh + 29600, nullptr, 18, 76, 20, ls, lq, lane, zp);
        }
      }
      *(f4*)(dbuf + kb * 2176 + ls * 68 + m0 + lq * 4) = Dh[0] + Dc[0] * INV;
      *(f4*)(dbuf + kb * 2176 + (16 + ls) * 68 + m0 + lq * 4) = Dh[1] + Dc[1] * INV;
      __syncthreads();
      const int b = lane;
      const float gr  = dbuf[wv * 68 + b]        + dbuf[2176 + wv * 68 + b]        + ebr;
      const float gz  = dbuf[(8 + wv) * 68 + b]  + dbuf[2176 + (8 + wv) * 68 + b]  + ebz;
      const float gni = dbuf[(16 + wv) * 68 + b] + dbuf[2176 + (16 + wv) * 68 + b] + ebni;
      const float gnh = dbuf[(24 + wv) * 68 + b] + dbuf[2176 + (24 + wv) * 68 + b] + ebnh;
      const float rg = 1.f / (1.f + expf(-gr));
      const float zg = 1.f / (1.f + expf(-gz));
      const float ng = tanhf(gni + rg * gnh);
      const float hn = (1.f - zg) * ng + zg * hreg;
      hreg = hn;
      tbuf[wv * 64 + b] = hn;
      __syncthreads();
      if (tid < 64) {
        const int oct = isL1 ? (128 + wg) : (wg - 128);
        f16* dst = encA + (size_t)(t & 1) * ESLOTH + ((size_t)oct * 64 + tid) * 8;
        h8 hv, lv;
#pragma unroll
        for (int e = 0; e < 8; ++e) { f16 hh, ll; fsplit(tbuf[e * 64 + tid], hh, ll); hv[e] = hh; lv[e] = ll; }
        *(h8*)dst = hv;
        *(h8*)(dst + (size_t)ELO * 512) = lv;
      }
    }
    gbar(bar, wg, phase);
  }

  // ============ fc -> hd0 (wg<128) ============
  if (wg < 128) {
    const int u0f = wg * 8;
    const int b = lane;
    float acc[8] = {0, 0, 0, 0, 0, 0, 0, 0};
    for (int ko = wv * 32; ko < wv * 32 + 32; ++ko) {
      const f16* hp = encA + ESLOTH + ((size_t)ko * 64 + b) * 8;
      const h8 hiv = *(const h8*)hp;
      const h8 lov = *(const h8*)(hp + (size_t)ELO * 512);
      float hv[8];
#pragma unroll
      for (int e = 0; e < 8; ++e) hv[e] = (float)hiv[e] + (float)lov[e] * INV;
#pragma unroll
      for (int u = 0; u < 8; ++u) {
        const float* wr = fcW + (size_t)(u0f + u) * 2048 + (size_t)ko * 8;
        const float4 wa = *(const float4*)wr, wb = *(const float4*)(wr + 4);
        acc[u] += hv[0] * wa.x + hv[1] * wa.y + hv[2] * wa.z + hv[3] * wa.w
                + hv[4] * wb.x + hv[5] * wb.y + hv[6] * wb.z + hv[7] * wb.w;
      }
    }
    __syncthreads();
#pragma unroll
    for (int u = 0; u < 8; ++u) dbuf[(u * 8 + wv) * 68 + b] = acc[u];
    __syncthreads();
    float sum = fcb[u0f + wv];
#pragma unroll
    for (int g = 0; g < 8; ++g) sum += dbuf[(wv * 8 + g) * 68 + lane];
    tbuf[wv * 64 + lane] = tanhf(sum);
    __syncthreads();
    if (tid < 64) {
      f16* dst = decA + ((size_t)wg * 64 + tid) * 8;   // slot0, oct = wg
      h8 hv, lv;
#pragma unroll
      for (int e = 0; e < 8; ++e) { f16 hh, ll; fsplit(tbuf[e * 64 + tid], hh, ll); hv[e] = hh; lv[e] = ll; }
      *(h8*)dst = hv;
      *(h8*)(dst + (size_t)DLO * 512) = lv;
    }
  }
  // stage decoder t=1 weights / proj weights
  if (wg < 128) stageDec(wh, wh + 33792, nullptr, dWhh, wg * 8, tid, true);
  else if (wg < 138) stageProj(wh, wh + 17408, pW, f0, tid);
  gbar(bar, wg, phase);   // publish decA slot0

  // decoder GRU step; hprev for t=1 from tbuf (fc output still resident in LDS)
  auto dec_step = [&](int t, bool first) {
    f4 Dh[2] = {{0.f,0.f,0.f,0.f},{0.f,0.f,0.f,0.f}};
    f4 Dc[2] = {{0.f,0.f,0.f,0.f},{0.f,0.f,0.f,0.f}};
    const f16* Ab = okf ? (stgX + (size_t)mb * 8)
                        : (decA + (size_t)((t - 1) & 1) * DSLOTH + (size_t)mb * 8);
    gmm<2, false, 33, false>(Dh, Dc, Ab, kb * 64, DLO, wh, wh + 33792, nullptr, 16, kb * 64, 0, ls, lq, lane, zp);
    *(f4*)(dbuf + kb * 2176 + ls * 68 + m0 + lq * 4) = Dh[0] + Dc[0] * INV;
    *(f4*)(dbuf + kb * 2176 + (16 + ls) * 68 + m0 + lq * 4) = Dh[1] + Dc[1] * INV;
    __syncthreads();
    const int b = lane;
    const float hprev = first ? tbuf[wv * 64 + b] : hdreg;
    const float gr  = dbuf[wv * 68 + b]        + dbuf[2176 + wv * 68 + b]        + (first ? b1r : bfr);
    const float gz  = dbuf[(8 + wv) * 68 + b]  + dbuf[2176 + (8 + wv) * 68 + b]  + (first ? b1z : bfz);
    const float gni = dbuf[(16 + wv) * 68 + b] + dbuf[2176 + (16 + wv) * 68 + b] + (first ? b1ni : bfni);
    const float gnh = dbuf[(24 + wv) * 68 + b] + dbuf[2176 + (24 + wv) * 68 + b] + (first ? b1nh : bfnh);
    const float rg = 1.f / (1.f + expf(-gr));
    const float zg = 1.f / (1.f + expf(-gz));
    const float ng = tanhf(gni + rg * gnh);
    const float hn = (1.f - zg) * ng + zg * hprev;
    hdreg = hn;
    tbuf[wv * 64 + b] = hn;
    __syncthreads();
    if (tid < 64) {
      f16* dst = decA + (size_t)(t & 1) * DSLOTH + ((size_t)wg * 64 + tid) * 8;
      h8 hv, lv;
#pragma unroll
      for (int e = 0; e < 8; ++e) { f16 hh, ll; fsplit(tbuf[e * 64 + tid], hh, ll); hv[e] = hh; lv[e] = ll; }
      *(h8*)dst = hv;
      *(h8*)(dst + (size_t)DLO * 512) = lv;
    }
  };

  auto proj = [&](int t2) {
    f4 Dh[1] = {{0.f,0.f,0.f,0.f}};
    f4 Dc[1] = {{0.f,0.f,0.f,0.f}};
    const f16* Ab = okf ? (stgX + (size_t)mb * 8)
                        : (decA + (size_t)((t2 - 1) & 1) * DSLOTH + (size_t)mb * 8);
    gmm<1, false, 17, false>(Dh, Dc, Ab, kb * 64, DLO, wh, wh + 17408, nullptr, 16, kb * 64, 0, ls, lq, lane, zp);
    *(f4*)(dbuf + kb * 2176 + ls * 68 + m0 + lq * 4) = Dh[0] + Dc[0] * INV;
    __syncthreads();
    if (tid < 256) {
      const int b2 = tid >> 2, fq = tid & 3;
      float4 o;
      o.x = dbuf[(fq * 4 + 0) * 68 + b2] + dbuf[2176 + (fq * 4 + 0) * 68 + b2] + pbr[0];
      o.y = dbuf[(fq * 4 + 1) * 68 + b2] + dbuf[2176 + (fq * 4 + 1) * 68 + b2] + pbr[1];
      o.z = dbuf[(fq * 4 + 2) * 68 + b2] + dbuf[2176 + (fq * 4 + 2) * 68 + b2] + pbr[2];
      o.w = dbuf[(fq * 4 + 3) * 68 + b2] + dbuf[2176 + (fq * 4 + 3) * 68 + b2] + pbr[3];
      *(float4*)(out + (size_t)b2 * (T_ * F_) + (size_t)(t2 - 2) * F_ + f0 + fq * 4) = o;
    }
  };

  // t = 1 (dWhh set), then swap in fused weights (LDS-local, no extra barrier)
  if (okf) { dec_copy(decA, stgX, 1, slotId, tid); lbar(bar, lphase, myx, slotId); }
  if (wg < 128) dec_step(1, true);
  gbar(bar, wg, phase);   // publish hd_1
  if (wg < 128) {
    stageDec(wh, wh + 33792, wdec, nullptr, wg * 8, tid, false);
    __syncthreads();
  }

  // ============ decoder main loop ============
  for (int t2 = 2; t2 <= T_ + 1; ++t2) {
    if (okf) { dec_copy(decA, stgX, t2, slotId, tid); lbar(bar, lphase, myx, slotId); }
    if (wg < 128) {
      if (t2 <= T_) dec_step(t2, false);
    } else if (wg < 138) {
      proj(t2);
    }
    gbar(bar, wg, phase);
  }
}

extern "C" void kernel_launch(void* const* d_in, const int* in_sizes, int n_in,
                              void* d_out, int out_size, void* d_ws, size_t ws_size,
                              hipStream_t stream) {
  (void)in_sizes; (void)n_in; (void)out_size;
  const float* x    = (const float*)d_in[0];
  const float* Wih0 = (const float*)d_in[1];
  const float* Whh0 = (const float*)d_in[2];
  const float* bih0 = (const float*)d_in[3];
  const float* bhh0 = (const float*)d_in[4];
  const float* Wih1 = (const float*)d_in[5];
  const float* Whh1 = (const float*)d_in[6];
  const float* bih1 = (const float*)d_in[7];
  const float* bhh1 = (const float*)d_in[8];
  const float* fcW  = (const float*)d_in[9];
  const float* fcb  = (const float*)d_in[10];
  const float* dWih = (const float*)d_in[11];
  const float* dWhh = (const float*)d_in[12];
  const float* dbih = (const float*)d_in[13];
  const float* dbhh = (const float*)d_in[14];
  const float* pW   = (const float*)d_in[15];
  const float* pb   = (const float*)d_in[16];
  float* out = (float*)d_out;
  char* wsb = (char*)d_ws;

  const int stgok = (ws_size >= WS_NEED) ? 1 : 0;

  hipFuncSetAttribute((const void*)speech_ae_persistent,
                      hipFuncAttributeMaxDynamicSharedMemorySize, LDS_B);
  hipMemsetAsync(d_ws, 0, 49152, stream);
  build_c_kernel<<<(3 * H_ + 255) / 256, 256, 0, stream>>>(dWih, dbih, pb, (float*)(wsb + WS_CVEC));
  build_wdec_kernel<<<(3 * H_ * 128 + 255) / 256, 256, 0, stream>>>(dWih, dWhh, pW, (float*)(wsb + WS_WDEC));
  build_wdec_nh<<<(H_ * H_ + 255) / 256, 256, 0, stream>>>(dWhh, (float*)(wsb + WS_WDEC));
  build_strm<<<32768, 256, 0, stream>>>(Wih1, Whh1, (f16*)(wsb + WS_STRM));
  speech_ae_persistent<<<NWG, NTH, LDS_B, stream>>>(
      x, Wih0, Whh0, bih0, bhh0, Wih1, Whh1, bih1, bhh1, fcW, fcb,
      dbih, dbhh, pW, pb, dWhh, out, d_ws, stgok);
}

// Round 13
// 38097.552 us; speedup vs baseline: 1.9236x; 1.9236x over previous
//
#include <hip/hip_runtime.h>
#include <math.h>

#define NWG 256
#define NTH 512
#define MASTER 255

typedef _Float16 f16;
typedef __attribute__((ext_vector_type(8))) _Float16 h8;
typedef __attribute__((ext_vector_type(4))) float f4;

namespace {
constexpr int T_ = 1024, F_ = 160, H_ = 1024;
constexpr float SC = 2048.f;
constexpr float INV = 1.f / 2048.f;

// state geometry (in halfs). layout: [oct][batch 64][8], hi octs then lo octs
constexpr int ESLOTH = 512 * 64 * 8;   // encoder slot: 256 hi + 256 lo octs
constexpr int DSLOTH = 256 * 64 * 8;   // decoder slot: 128 hi + 128 lo octs
constexpr int ELO = 256;               // lo oct offset (encoder)
constexpr int DLO = 128;               // lo oct offset (decoder)

// ws byte offsets.  bar region: 256 per-WG flags at dword wg*32 (128 B apart)
// + gen at dword 8192.  32896 B total, memset each launch.
constexpr size_t WS_BAR  = 0;
constexpr size_t WS_CVEC = 32896;                                // 3H f32
constexpr size_t WS_WDEC = WS_CVEC + 12288;                      // 4H*H f32
constexpr size_t WS_ENCA = WS_WDEC + (size_t)4 * H_ * H_ * 4;    // 2 slots
constexpr size_t WS_DECA = WS_ENCA + (size_t)2 * ESLOTH * 2;
constexpr size_t WS_STRM = WS_DECA + (size_t)2 * DSLOTH * 2;
// strm: 128 wg * 2 kb * 32 kt * 2 nt * 64 lanes * 8 halfs = 8388608 halfs

// LDS byte offsets (fixed across roles)
constexpr int DBUF_B = 135168;           // f32[2][32][68]
constexpr int TBUF_B = DBUF_B + 17408;   // f32[8][64]
constexpr int ZP_B   = TBUF_B + 2048;    // 16 halfs of zeros
constexpr int LDS_B  = ZP_B + 64;
}

__device__ __forceinline__ f4 MF(h8 a, h8 b, f4 c) {
  return __builtin_amdgcn_mfma_f32_16x16x32_f16(a, b, c, 0, 0, 0);
}

// split v into fp16 hi (0 if would be denormal) + fp16 lo' scaled by 2048
__device__ __forceinline__ void fsplit(float v, f16& hi, f16& lo) {
  const float hf = (fabsf(v) >= 6.103515625e-05f) ? (float)(f16)v : 0.f;
  hi = (f16)hf;
  lo = (f16)((v - hf) * SC);
}

// ---- grid barrier: flag-array + master scan (R11, proven). ----
__device__ __forceinline__ void gbar(unsigned* bar, int wg, unsigned& phase) {
  __syncthreads();
  ++phase;
  const int tid = threadIdx.x;
  unsigned* gen = bar + 8192;
  if (wg == MASTER) {
    if (tid == 0)
      __hip_atomic_store(&bar[MASTER * 32], phase, __ATOMIC_RELEASE, __HIP_MEMORY_SCOPE_AGENT);
    if (tid < 256) {
      while (__hip_atomic_load(&bar[tid * 32], __ATOMIC_RELAXED, __HIP_MEMORY_SCOPE_AGENT) < phase)
        __builtin_amdgcn_s_sleep(1);
    }
    __syncthreads();
    if (tid == 0) {
      __hip_atomic_store(gen, phase, __ATOMIC_RELEASE, __HIP_MEMORY_SCOPE_AGENT);
      (void)__hip_atomic_load(gen, __ATOMIC_ACQUIRE, __HIP_MEMORY_SCOPE_AGENT);
    }
  } else {
    if (tid == 0) {
      __hip_atomic_store(&bar[wg * 32], phase, __ATOMIC_RELEASE, __HIP_MEMORY_SCOPE_AGENT);
      while (__hip_atomic_load(gen, __ATOMIC_RELAXED, __HIP_MEMORY_SCOPE_AGENT) < phase)
        __builtin_amdgcn_s_sleep(1);
      (void)__hip_atomic_load(gen, __ATOMIC_ACQUIRE, __HIP_MEMORY_SCOPE_AGENT);
    }
  }
  __syncthreads();
}

// ---- staging: f32 weights -> fp16 hi/lo pairs in LDS ----
// encoder packed 24-slot rows (pad to 25): slots 0..15 = r,z ; 16..23 = ni(x-side)/nh(h-side)
__device__ void stageEnc(f16* __restrict__ whi, f16* __restrict__ wlo,
                         const float* __restrict__ Wx, const float* __restrict__ Wh,
                         int KX, int XOo, int KO, int u0, int tid) {
  for (int task = tid; task < KO * 24; task += NTH) {
    const int oct = task / 24;
    const int sl = task - oct * 24;
    const int g = (sl < 16) ? (sl >> 3) : 2;
    const int u = u0 + (sl & 7);
    const float* src = (oct < XOo)
        ? (Wx + (size_t)(g * H_ + u) * KX + (size_t)oct * 8)
        : (Wh + (size_t)(g * H_ + u) * H_ + (size_t)(oct - XOo) * 8);
    const float4 a = *(const float4*)src;
    const float4 b = *(const float4*)(src + 4);
    const float v[8] = {a.x, a.y, a.z, a.w, b.x, b.y, b.z, b.w};
    h8 hv, lv;
#pragma unroll
    for (int e = 0; e < 8; ++e) { f16 hh, ll; fsplit(v[e], hh, ll); hv[e] = hh; lv[e] = ll; }
    *(h8*)(whi + ((size_t)oct * 25 + sl) * 8) = hv;
    if (wlo) *(h8*)(wlo + ((size_t)oct * 25 + sl) * 8) = lv;
  }
}

// decoder 32-slot rows (pad 33): slots g*8+j, g in {r,z,ni,nh}, full K
__device__ void stageDec(f16* __restrict__ whi, f16* __restrict__ wlo,
                         const float* __restrict__ wdec, const float* __restrict__ dWhh,
                         int u0, int tid, bool t1set) {
  for (int task = tid; task < 128 * 32; task += NTH) {
    const int oct = task >> 5, sl = task & 31;
    const int g = sl >> 3;
    const int u = u0 + (sl & 7);
    float v[8];
    if (t1set) {
      if (g == 2) {
#pragma unroll
        for (int e = 0; e < 8; ++e) v[e] = 0.f;
      } else {
        const float* s = dWhh + (size_t)((g == 3 ? 2 : g) * H_ + u) * H_ + (size_t)oct * 8;
        const float4 a = *(const float4*)s, b = *(const float4*)(s + 4);
        v[0]=a.x; v[1]=a.y; v[2]=a.z; v[3]=a.w; v[4]=b.x; v[5]=b.y; v[6]=b.z; v[7]=b.w;
      }
    } else {
      const float* s = wdec + (size_t)(g * H_ + u) * H_ + (size_t)oct * 8;
      const float4 a = *(const float4*)s, b = *(const float4*)(s + 4);
      v[0]=a.x; v[1]=a.y; v[2]=a.z; v[3]=a.w; v[4]=b.x; v[5]=b.y; v[6]=b.z; v[7]=b.w;
    }
    h8 hv, lv;
#pragma unroll
    for (int e = 0; e < 8; ++e) { f16 hh, ll; fsplit(v[e], hh, ll); hv[e] = hh; lv[e] = ll; }
    *(h8*)(whi + ((size_t)oct * 33 + sl) * 8) = hv;
    *(h8*)(wlo + ((size_t)oct * 33 + sl) * 8) = lv;
  }
}

__device__ void stageProj(f16* __restrict__ whi, f16* __restrict__ wlo,
                          const float* __restrict__ pW, int f0, int tid) {
  for (int task = tid; task < 128 * 16; task += NTH) {
    const int oct = task >> 4, sl = task & 15;
    const float* s = pW + (size_t)(f0 + sl) * H_ + (size_t)oct * 8;
    const float4 a = *(const float4*)s, b = *(const float4*)(s + 4);
    const float v[8] = {a.x, a.y, a.z, a.w, b.x, b.y, b.z, b.w};
    h8 hv, lv;
#pragma unroll
    for (int e = 0; e < 8; ++e) { f16 hh, ll; fsplit(v[e], hh, ll); hv[e] = hh; lv[e] = ll; }
    *(h8*)(whi + ((size_t)oct * 17 + sl) * 8) = hv;
    *(h8*)(wlo + ((size_t)oct * 17 + sl) * 8) = lv;
  }
}

// ---- MFMA k-phase, 2 m-tiles per wave (rows mb and mb+16), K quarter per
// wave.  1-deep pipeline (locality-safe); chain length halved vs R11. ----
template<int NT, bool NSPLIT, int ROWH, bool STRM>
__device__ __forceinline__ void gmm(f4 Dh[2][2], f4 Dc[2][2],
    const f16* __restrict__ Ab, int aoctBase, int loOct,
    const f16* __restrict__ whi, const f16* __restrict__ wlo,
    const f16* __restrict__ strm,
    int ktn, int octBase, int XO, int ls, int lq, int lane,
    const f16* __restrict__ zp) {
  auto LD = [&](int kk, h8& a0, h8& l0, h8& a1, h8& l1,
                h8& bh0, h8& bl0, h8& bh1, h8& bl1) {
    const int aoct = aoctBase + kk * 4 + lq;
    const f16* ap = Ab + (size_t)aoct * 512;
    const f16* lp = Ab + (size_t)(aoct + loOct) * 512;
    a0 = *(const h8*)ap;
    a1 = *(const h8*)(ap + 128);
    l0 = *(const h8*)lp;
    l1 = *(const h8*)(lp + 128);
    const int oct = octBase + kk * 4 + lq;
    bh0 = *(const h8*)(whi + ((size_t)oct * ROWH + ls) * 8);
    if constexpr (STRM) bl0 = *(const h8*)(strm + ((size_t)(kk * 2) * 64 + lane) * 8);
    else bl0 = *(const h8*)(wlo + ((size_t)oct * ROWH + ls) * 8);
    if constexpr (NT == 2) {
      bool act = true; int psl;
      if constexpr (NSPLIT) { act = (ls < 8) ? (oct < XO) : (oct >= XO); psl = 16 + (ls & 7); }
      else { psl = 16 + ls; }
      bh1 = *(const h8*)(act ? (whi + ((size_t)oct * ROWH + psl) * 8) : zp);
      if constexpr (STRM) bl1 = *(const h8*)(strm + ((size_t)(kk * 2 + 1) * 64 + lane) * 8);
      else bl1 = *(const h8*)(act ? (wlo + ((size_t)oct * ROWH + psl) * 8) : zp);
    }
  };
  h8 a0, l0, a1, l1, bh0, bl0, bh1, bl1;
  LD(0, a0, l0, a1, l1, bh0, bl0, bh1, bl1);
  for (int kk = 0; kk < ktn; ++kk) {
    h8 a0n, l0n, a1n, l1n, bh0n, bl0n, bh1n, bl1n;
    const int nk = (kk + 1 < ktn) ? (kk + 1) : kk;
    LD(nk, a0n, l0n, a1n, l1n, bh0n, bl0n, bh1n, bl1n);
    Dh[0][0] = MF(a0, bh0, Dh[0][0]);
    Dc[0][0] = MF(l0, bh0, Dc[0][0]);
    Dc[0][0] = MF(a0, bl0, Dc[0][0]);
    Dh[1][0] = MF(a1, bh0, Dh[1][0]);
    Dc[1][0] = MF(l1, bh0, Dc[1][0]);
    Dc[1][0] = MF(a1, bl0, Dc[1][0]);
    if constexpr (NT == 2) {
      Dh[0][1] = MF(a0, bh1, Dh[0][1]);
      Dc[0][1] = MF(l0, bh1, Dc[0][1]);
      Dc[0][1] = MF(a0, bl1, Dc[0][1]);
      Dh[1][1] = MF(a1, bh1, Dh[1][1]);
      Dc[1][1] = MF(l1, bh1, Dc[1][1]);
      Dc[1][1] = MF(a1, bl1, Dc[1][1]);
    }
    a0 = a0n; l0 = l0n; a1 = a1n; l1 = l1n; bh0 = bh0n; bl0 = bl0n;
    if constexpr (NT == 2) { bh1 = bh1n; bl1 = bl1n; }
  }
}

// encoder L0 x-part, 2 m-tiles: f32 x -> in-register hi/lo, W octs 0..19
__device__ __forceinline__ void gmm_x2(f4 Dh[2][2], f4 Dc[2][2],
    const float* __restrict__ xp0, const float* __restrict__ xp1,
    const f16* __restrict__ whi, const f16* __restrict__ wlo,
    int ls, int lq, const f16* __restrict__ zp) {
#pragma unroll
  for (int kk = 0; kk < 5; ++kk) {
    h8 am[2], lm[2];
#pragma unroll
    for (int mt = 0; mt < 2; ++mt) {
      const float* xp = mt ? xp1 : xp0;
      const float4 a = *(const float4*)(xp + kk * 32);
      const float4 b = *(const float4*)(xp + kk * 32 + 4);
      const float v[8] = {a.x, a.y, a.z, a.w, b.x, b.y, b.z, b.w};
#pragma unroll
      for (int e = 0; e < 8; ++e) { f16 hh, ll; fsplit(v[e], hh, ll); am[mt][e] = hh; lm[mt][e] = ll; }
    }
    const int oct = kk * 4 + lq;
    {
      const h8 bh2 = *(const h8*)(whi + ((size_t)oct * 25 + ls) * 8);
      const h8 bl2 = *(const h8*)(wlo + ((size_t)oct * 25 + ls) * 8);
#pragma unroll
      for (int mt = 0; mt < 2; ++mt) {
        Dh[mt][0] = MF(am[mt], bh2, Dh[mt][0]);
        Dc[mt][0] = MF(lm[mt], bh2, Dc[mt][0]);
        Dc[mt][0] = MF(am[mt], bl2, Dc[mt][0]);
      }
    }
    {
      const bool act = (ls < 8);
      const int psl = 16 + (ls & 7);
      const h8 bh2 = *(const h8*)(act ? (whi + ((size_t)oct * 25 + psl) * 8) : zp);
      const h8 bl2 = *(const h8*)(act ? (wlo + ((size_t)oct * 25 + psl) * 8) : zp);
#pragma unroll
      for (int mt = 0; mt < 2; ++mt) {
        Dh[mt][1] = MF(am[mt], bh2, Dh[mt][1]);
        Dc[mt][1] = MF(lm[mt], bh2, Dc[mt][1]);
        Dc[mt][1] = MF(am[mt], bl2, Dc[mt][1]);
      }
    }
  }
}

// ---- setup kernels ----
__global__ void build_c_kernel(const float* __restrict__ dWih, const float* __restrict__ dbih,
                               const float* __restrict__ pb, float* __restrict__ cvec) {
  const int r = blockIdx.x * 256 + threadIdx.x;
  if (r >= 3 * H_) return;
  float a = dbih[r];
  for (int f = 0; f < F_; ++f) a += dWih[(size_t)r * F_ + f] * pb[f];
  cvec[r] = a;
}

__global__ void build_wdec_kernel(const float* __restrict__ dWih, const float* __restrict__ dWhh,
                                  const float* __restrict__ pW, float* __restrict__ wdec) {
  const int idx = blockIdx.x * 256 + threadIdx.x;
  if (idx >= 3 * H_ * 128) return;
  const int row = idx >> 7;
  const int oct = idx & 127;
  float v[8] = {0, 0, 0, 0, 0, 0, 0, 0};
  const float* wr = dWih + (size_t)row * F_;
  for (int f = 0; f < F_; ++f) {
    const float w = wr[f];
    const float4 p0 = *(const float4*)(pW + (size_t)f * H_ + oct * 8);
    const float4 p1 = *(const float4*)(pW + (size_t)f * H_ + oct * 8 + 4);
    v[0] += w * p0.x; v[1] += w * p0.y; v[2] += w * p0.z; v[3] += w * p0.w;
    v[4] += w * p1.x; v[5] += w * p1.y; v[6] += w * p1.z; v[7] += w * p1.w;
  }
  if ((row >> 10) < 2) {
    const float* hr = dWhh + (size_t)row * H_ + oct * 8;
#pragma unroll
    for (int e = 0; e < 8; ++e) v[e] += hr[e];
  }
  float* o = wdec + (size_t)row * H_ + oct * 8;
#pragma unroll
  for (int e = 0; e < 8; ++e) o[e] = v[e];
}
__global__ void build_wdec_nh(const float* __restrict__ dWhh, float* __restrict__ wdec) {
  const int idx = blockIdx.x * 256 + threadIdx.x;
  if (idx >= H_ * H_) return;
  wdec[(size_t)3 * H_ * H_ + idx] = dWhh[(size_t)2 * H_ * H_ + idx];
}

// L1 lo-fragment stream, fragment-ordered: [(wg*2+kb)*32768 + ((kk*2+nt)*64+lane)*8 + j]
__global__ void build_strm(const float* __restrict__ Wih1, const float* __restrict__ Whh1,
                           f16* __restrict__ strm) {
  const size_t idx = (size_t)blockIdx.x * 256 + threadIdx.x;  // 8388608 total
  const int j = (int)(idx & 7);
  const int lane = (int)((idx >> 3) & 63);
  const int nt = (int)((idx >> 9) & 1);
  const int kk = (int)((idx >> 10) & 31);
  const int kb = (int)((idx >> 15) & 1);
  const int wg = (int)(idx >> 16);
  const int c = lane & 15, lq = lane >> 4;
  const int oct = kb * 128 + kk * 4 + lq;
  const int k = oct * 8 + j;
  float v = 0.f;
  if (nt == 0) {
    const int row = (c >> 3) * H_ + wg * 8 + (c & 7);
    v = (oct < 128) ? Wih1[(size_t)row * H_ + k] : Whh1[(size_t)row * H_ + (k - 1024)];
  } else {
    const bool act = (c < 8) ? (oct < 128) : (oct >= 128);
    if (act) {
      const int row = 2 * H_ + wg * 8 + (c & 7);
      v = (oct < 128) ? Wih1[(size_t)row * H_ + k] : Whh1[(size_t)row * H_ + (k - 1024)];
    }
  }
  f16 hh, ll; fsplit(v, hh, ll);
  strm[idx] = ll;
}

// ---- persistent kernel: 8 waves = 2 m-groups x 4 k-groups ----
__global__ void __launch_bounds__(NTH, 1) speech_ae_persistent(
    const float* __restrict__ x,
    const float* __restrict__ Wih0, const float* __restrict__ Whh0,
    const float* __restrict__ bih0, const float* __restrict__ bhh0,
    const float* __restrict__ Wih1, const float* __restrict__ Whh1,
    const float* __restrict__ bih1, const float* __restrict__ bhh1,
    const float* __restrict__ fcW, const float* __restrict__ fcb,
    const float* __restrict__ dbih, const float* __restrict__ dbhh,
    const float* __restrict__ pW, const float* __restrict__ pb,
    const float* __restrict__ dWhh,
    float* __restrict__ out, void* ws) {
  extern __shared__ char ldsb[];
  f16* wh = (f16*)ldsb;
  float* dbuf = (float*)(ldsb + DBUF_B);
  float* tbuf = (float*)(ldsb + TBUF_B);
  f16* zp = (f16*)(ldsb + ZP_B);

  char* wsb = (char*)ws;
  unsigned* bar = (unsigned*)(wsb + WS_BAR);
  const float* cvec = (const float*)(wsb + WS_CVEC);
  const float* wdec = (const float*)(wsb + WS_WDEC);
  f16* encA = (f16*)(wsb + WS_ENCA);
  f16* decA = (f16*)(wsb + WS_DECA);
  const f16* strm = (const f16*)(wsb + WS_STRM);

  const int tid = threadIdx.x, wg = blockIdx.x;
  const int lane = tid & 63, wv = tid >> 6;
  const int ls = lane & 15, lq = lane >> 4;
  const int mg = wv & 1, kg = wv >> 1;      // 2 m-groups x 4 k-groups
  const int m0 = mg * 32;
  const int mb = m0 + ls;                   // m-tile0 row; m-tile1 = mb+16
  const bool isL1 = (wg < 128);
  unsigned phase = 0;
  // L1 strm quarter: old kb = kg>>1, half = kg&1 (16 kts = 16384 halfs)
  const f16* strmQ = strm + (size_t)(wg * 2 + (kg >> 1)) * 32768 + (size_t)(kg & 1) * 16384;

  // encoder biases (8 units/WG; thread's unit = wv)
  const float* bi = isL1 ? bih1 : bih0;
  const float* bh_ = isL1 ? bhh1 : bhh0;
  const int eru = (isL1 ? wg * 8 : (wg - 128) * 8) + wv;
  const float ebr = bi[eru] + bh_[eru];
  const float ebz = bi[H_ + eru] + bh_[H_ + eru];
  const float ebni = bi[2 * H_ + eru];
  const float ebnh = bh_[2 * H_ + eru];
  float hreg = 0.f;

  // decoder biases
  float b1r = 0, b1z = 0, b1ni = 0, b1nh = 0, bfr = 0, bfz = 0, bfni = 0, bfnh = 0, hdreg = 0.f;
  if (wg < 128) {
    const int rw = wg * 8 + wv;
    b1r = dbih[rw] + dbhh[rw];
    b1z = dbih[H_ + rw] + dbhh[H_ + rw];
    b1ni = dbih[2 * H_ + rw];
    b1nh = dbhh[2 * H_ + rw];
    bfr = cvec[rw] + dbhh[rw];
    bfz = cvec[H_ + rw] + dbhh[H_ + rw];
    bfni = cvec[2 * H_ + rw];
    bfnh = dbhh[2 * H_ + rw];
  }
  const int f0 = (wg - 128) * 16;
  float pbr[4] = {0, 0, 0, 0};
  if (wg >= 128 && wg < 138 && tid < 256) {
    const int fq = tid & 3;
#pragma unroll
    for (int e = 0; e < 4; ++e) pbr[e] = pb[f0 + fq * 4 + e];
  }

  // stage encoder weights
  if (isL1) stageEnc(wh, nullptr, Wih1, Whh1, H_, 128, 256, wg * 8, tid);
  else stageEnc(wh, wh + 29600, Wih0, Whh0, F_, 20, 148, (wg - 128) * 8, tid);
  if (tid < 16) zp[tid] = (f16)0.f;
  __syncthreads();

  // two-phase partial-sum combine: kg0/1 write halves 0/1, sync, kg2/3 add.
  auto combine = [&](f4 Dh[2][2], f4 Dc[2][2], int NTv) {
    float* dp = dbuf + (kg & 1) * 2176;
    const int c0 = m0 + lq * 4;
    if (kg < 2) {
      for (int mt = 0; mt < 2; ++mt)
        for (int nt = 0; nt < NTv; ++nt)
          *(f4*)(dp + (nt * 16 + ls) * 68 + c0 + mt * 16) = Dh[mt][nt] + Dc[mt][nt] * INV;
    }
    __syncthreads();
    if (kg >= 2) {
      for (int mt = 0; mt < 2; ++mt)
        for (int nt = 0; nt < NTv; ++nt) {
          f4* p = (f4*)(dp + (nt * 16 + ls) * 68 + c0 + mt * 16);
          *p = *p + Dh[mt][nt] + Dc[mt][nt] * INV;
        }
    }
    __syncthreads();
  };

  const f4 Z = {0.f, 0.f, 0.f, 0.f};

  // ============ encoder: L0 (wg>=128) at t=s, L1 (wg<128) at t=s-1 ============
  for (int s = 0; s <= T_; ++s) {
    const bool active = isL1 ? (s >= 1) : (s < T_);
    if (active) {
      const int t = isL1 ? (s - 1) : s;
      f4 Dh[2][2] = {{Z, Z}, {Z, Z}};
      f4 Dc[2][2] = {{Z, Z}, {Z, Z}};
      if (isL1) {
        if (kg < 2) {         // h0_t, W octs kg*64..+64
          const f16* Ab = encA + (size_t)(t & 1) * ESLOTH + (size_t)mb * 8;
          gmm<2, true, 25, true>(Dh, Dc, Ab, kg * 64, ELO, wh, nullptr, strmQ, 16, kg * 64, 128, ls, lq, lane, zp);
        } else if (t >= 1) {  // h1_{t-1}, W octs kg*64..+64 (128..255)
          const f16* Ab = encA + (size_t)((t - 1) & 1) * ESLOTH + (size_t)mb * 8;
          gmm<2, true, 25, true>(Dh, Dc, Ab, kg * 64, ELO, wh, nullptr, strmQ, 16, kg * 64, 128, ls, lq, lane, zp);
        }
      } else {
        const f16* Ab = encA + (size_t)((s - 1) & 1) * ESLOTH + (size_t)mb * 8;
        if (kg == 0) {
          const float* xp0 = x + ((size_t)mb * T_ + t) * F_ + lq * 8;
          const float* xp1 = xp0 + (size_t)16 * T_ * F_;
          gmm_x2(Dh, Dc, xp0, xp1, wh, wh + 29600, ls, lq, zp);
          if (t >= 1)
            gmm<2, true, 25, false>(Dh, Dc, Ab, 0, ELO, wh, wh + 29600, nullptr, 5, 20, 20, ls, lq, lane, zp);
        } else if (t >= 1) {
          const int ao = 20 + (kg - 1) * 36;   // 20, 56, 92
          gmm<2, true, 25, false>(Dh, Dc, Ab, ao, ELO, wh, wh + 29600, nullptr, 9, 20 + ao, 20, ls, lq, lane, zp);
        }
      }
      combine(Dh, Dc, 2);
      const int b = lane;
      const float gr  = dbuf[wv * 68 + b]        + dbuf[2176 + wv * 68 + b]        + ebr;
      const float gz  = dbuf[(8 + wv) * 68 + b]  + dbuf[2176 + (8 + wv) * 68 + b]  + ebz;
      const float gni = dbuf[(16 + wv) * 68 + b] + dbuf[2176 + (16 + wv) * 68 + b] + ebni;
      const float gnh = dbuf[(24 + wv) * 68 + b] + dbuf[2176 + (24 + wv) * 68 + b] + ebnh;
      const float rg = 1.f / (1.f + expf(-gr));
      const float zg = 1.f / (1.f + expf(-gz));
      const float ng = tanhf(gni + rg * gnh);
      const float hn = (1.f - zg) * ng + zg * hreg;
      hreg = hn;
      tbuf[wv * 64 + b] = hn;
      __syncthreads();
      if (tid < 64) {
        const int oct = isL1 ? (128 + wg) : (wg - 128);
        f16* dst = encA + (size_t)(t & 1) * ESLOTH + ((size_t)oct * 64 + tid) * 8;
        h8 hv, lv;
#pragma unroll
        for (int e = 0; e < 8; ++e) { f16 hh, ll; fsplit(tbuf[e * 64 + tid], hh, ll); hv[e] = hh; lv[e] = ll; }
        *(h8*)dst = hv;
        *(h8*)(dst + (size_t)ELO * 512) = lv;
      }
    }
    gbar(bar, wg, phase);
  }

  // ============ fc -> hd0 (wg<128) ============
  if (wg < 128) {
    const int u0f = wg * 8;
    const int b = lane;
    float acc[8] = {0, 0, 0, 0, 0, 0, 0, 0};
    for (int ko = wv * 32; ko < wv * 32 + 32; ++ko) {
      const f16* hp = encA + ESLOTH + ((size_t)ko * 64 + b) * 8;
      const h8 hiv = *(const h8*)hp;
      const h8 lov = *(const h8*)(hp + (size_t)ELO * 512);
      float hv[8];
#pragma unroll
      for (int e = 0; e < 8; ++e) hv[e] = (float)hiv[e] + (float)lov[e] * INV;
#pragma unroll
      for (int u = 0; u < 8; ++u) {
        const float* wr = fcW + (size_t)(u0f + u) * 2048 + (size_t)ko * 8;
        const float4 wa = *(const float4*)wr, wb = *(const float4*)(wr + 4);
        acc[u] += hv[0] * wa.x + hv[1] * wa.y + hv[2] * wa.z + hv[3] * wa.w
                + hv[4] * wb.x + hv[5] * wb.y + hv[6] * wb.z + hv[7] * wb.w;
      }
    }
    __syncthreads();
#pragma unroll
    for (int u = 0; u < 8; ++u) dbuf[(u * 8 + wv) * 68 + b] = acc[u];
    __syncthreads();
    float sum = fcb[u0f + wv];
#pragma unroll
    for (int g = 0; g < 8; ++g) sum += dbuf[(wv * 8 + g) * 68 + lane];
    tbuf[wv * 64 + lane] = tanhf(sum);
    __syncthreads();
    if (tid < 64) {
      f16* dst = decA + ((size_t)wg * 64 + tid) * 8;   // slot0, oct = wg
      h8 hv, lv;
#pragma unroll
      for (int e = 0; e < 8; ++e) { f16 hh, ll; fsplit(tbuf[e * 64 + tid], hh, ll); hv[e] = hh; lv[e] = ll; }
      *(h8*)dst = hv;
      *(h8*)(dst + (size_t)DLO * 512) = lv;
    }
  }
  // stage decoder t=1 weights / proj weights
  if (wg < 128) stageDec(wh, wh + 33792, nullptr, dWhh, wg * 8, tid, true);
  else if (wg < 138) stageProj(wh, wh + 17408, pW, f0, tid);
  gbar(bar, wg, phase);   // publish decA slot0

  // decoder GRU step; hprev for t=1 from tbuf (fc output still resident in LDS)
  auto dec_step = [&](int t, bool first) {
    f4 Dh[2][2] = {{Z, Z}, {Z, Z}};
    f4 Dc[2][2] = {{Z, Z}, {Z, Z}};
    const f16* Ab = decA + (size_t)((t - 1) & 1) * DSLOTH + (size_t)mb * 8;
    gmm<2, false, 33, false>(Dh, Dc, Ab, kg * 32, DLO, wh, wh + 33792, nullptr, 8, kg * 32, 0, ls, lq, lane, zp);
    combine(Dh, Dc, 2);
    const int b = lane;
    const float hprev = first ? tbuf[wv * 64 + b] : hdreg;
    const float gr  = dbuf[wv * 68 + b]        + dbuf[2176 + wv * 68 + b]        + (first ? b1r : bfr);
    const float gz  = dbuf[(8 + wv) * 68 + b]  + dbuf[2176 + (8 + wv) * 68 + b]  + (first ? b1z : bfz);
    const float gni = dbuf[(16 + wv) * 68 + b] + dbuf[2176 + (16 + wv) * 68 + b] + (first ? b1ni : bfni);
    const float gnh = dbuf[(24 + wv) * 68 + b] + dbuf[2176 + (24 + wv) * 68 + b] + (first ? b1nh : bfnh);
    const float rg = 1.f / (1.f + expf(-gr));
    const float zg = 1.f / (1.f + expf(-gz));
    const float ng = tanhf(gni + rg * gnh);
    const float hn = (1.f - zg) * ng + zg * hprev;
    hdreg = hn;
    tbuf[wv * 64 + b] = hn;
    __syncthreads();
    if (tid < 64) {
      f16* dst = decA + (size_t)(t & 1) * DSLOTH + ((size_t)wg * 64 + tid) * 8;
      h8 hv, lv;
#pragma unroll
      for (int e = 0; e < 8; ++e) { f16 hh, ll; fsplit(tbuf[e * 64 + tid], hh, ll); hv[e] = hh; lv[e] = ll; }
      *(h8*)dst = hv;
      *(h8*)(dst + (size_t)DLO * 512) = lv;
    }
  };

  auto proj = [&](int t2) {
    f4 Dh[2][2] = {{Z, Z}, {Z, Z}};
    f4 Dc[2][2] = {{Z, Z}, {Z, Z}};
    const f16* Ab = decA + (size_t)((t2 - 1) & 1) * DSLOTH + (size_t)mb * 8;
    gmm<1, false, 17, false>(Dh, Dc, Ab, kg * 32, DLO, wh, wh + 17408, nullptr, 8, kg * 32, 0, ls, lq, lane, zp);
    combine(Dh, Dc, 1);
    if (tid < 256) {
      const int b2 = tid >> 2, fq = tid & 3;
      float4 o;
      o.x = dbuf[(fq * 4 + 0) * 68 + b2] + dbuf[2176 + (fq * 4 + 0) * 68 + b2] + pbr[0];
      o.y = dbuf[(fq * 4 + 1) * 68 + b2] + dbuf[2176 + (fq * 4 + 1) * 68 + b2] + pbr[1];
      o.z = dbuf[(fq * 4 + 2) * 68 + b2] + dbuf[2176 + (fq * 4 + 2) * 68 + b2] + pbr[2];
      o.w = dbuf[(fq * 4 + 3) * 68 + b2] + dbuf[2176 + (fq * 4 + 3) * 68 + b2] + pbr[3];
      *(float4*)(out + (size_t)b2 * (T_ * F_) + (size_t)(t2 - 2) * F_ + f0 + fq * 4) = o;
    }
  };

  // t = 1 (dWhh set), then swap in fused weights (LDS-local, no extra barrier)
  if (wg < 128) dec_step(1, true);
  gbar(bar, wg, phase);   // publish hd_1
  if (wg < 128) {
    stageDec(wh, wh + 33792, wdec, nullptr, wg * 8, tid, false);
    __syncthreads();
  }

  // ============ decoder main loop ============
  for (int t2 = 2; t2 <= T_ + 1; ++t2) {
    if (wg < 128) {
      if (t2 <= T_) dec_step(t2, false);
    } else if (wg < 138) {
      proj(t2);
    }
    gbar(bar, wg, phase);
  }
}

extern "C" void kernel_launch(void* const* d_in, const int* in_sizes, int n_in,
                              void* d_out, int out_size, void* d_ws, size_t ws_size,
                              hipStream_t stream) {
  (void)in_sizes; (void)n_in; (void)out_size; (void)ws_size;
  const float* x    = (const float*)d_in[0];
  const float* Wih0 = (const float*)d_in[1];
  const float* Whh0 = (const float*)d_in[2];
  const float* bih0 = (const float*)d_in[3];
  const float* bhh0 = (const float*)d_in[4];
  const float* Wih1 = (const float*)d_in[5];
  const float* Whh1 = (const float*)d_in[6];
  const float* bih1 = (const float*)d_in[7];
  const float* bhh1 = (const float*)d_in[8];
  const float* fcW  = (const float*)d_in[9];
  const float* fcb  = (const float*)d_in[10];
  const float* dWih = (const float*)d_in[11];
  const float* dWhh = (const float*)d_in[12];
  const float* dbih = (const float*)d_in[13];
  const float* dbhh = (const float*)d_in[14];
  const float* pW   = (const float*)d_in[15];
  const float* pb   = (const float*)d_in[16];
  float* out = (float*)d_out;
  char* wsb = (char*)d_ws;

  hipFuncSetAttribute((const void*)speech_ae_persistent,
                      hipFuncAttributeMaxDynamicSharedMemorySize, LDS_B);
  hipMemsetAsync(d_ws, 0, 32896, stream);
  build_c_kernel<<<(3 * H_ + 255) / 256, 256, 0, stream>>>(dWih, dbih, pb, (float*)(wsb + WS_CVEC));
  build_wdec_kernel<<<(3 * H_ * 128 + 255) / 256, 256, 0, stream>>>(dWih, dWhh, pW, (float*)(wsb + WS_WDEC));
  build_wdec_nh<<<(H_ * H_ + 255) / 256, 256, 0, stream>>>(dWhh, (float*)(wsb + WS_WDEC));
  build_strm<<<32768, 256, 0, stream>>>(Wih1, Whh1, (f16*)(wsb + WS_STRM));
  speech_ae_persistent<<<NWG, NTH, LDS_B, stream>>>(
      x, Wih0, Whh0, bih0, bhh0, Wih1, Whh1, bih1, bhh1, fcW, fcb,
      dbih, dbhh, pW, pb, dWhh, out, d_ws);
}

// Round 14
// 36154.095 us; speedup vs baseline: 2.0270x; 1.0538x over previous
//
#include <hip/hip_runtime.h>
#include <math.h>

#define NWG 256
#define NTH 512
#define MASTER 255

typedef _Float16 f16;
typedef __attribute__((ext_vector_type(8))) _Float16 h8;
typedef __attribute__((ext_vector_type(4))) float f4;

namespace {
constexpr int T_ = 1024, F_ = 160, H_ = 1024;
constexpr float SC = 2048.f;
constexpr float INV = 1.f / 2048.f;

// state geometry (in halfs). layout: [oct][batch 64][8], hi octs then lo octs
constexpr int ESLOTH = 512 * 64 * 8;   // encoder slot: 256 hi + 256 lo octs
constexpr int DSLOTH = 256 * 64 * 8;   // decoder slot: 128 hi + 128 lo octs
constexpr int ELO = 256;               // lo oct offset (encoder)
constexpr int DLO = 128;               // lo oct offset (decoder)

// ws byte offsets.  bar region: 256 per-WG flags at dword wg*32 (128 B apart)
// + gen at dword 8192.  32896 B total, memset each launch.
constexpr size_t WS_BAR  = 0;
constexpr size_t WS_CVEC = 32896;                                // 3H f32
constexpr size_t WS_WDEC = WS_CVEC + 12288;                      // 4H*H f32
constexpr size_t WS_ENCA = WS_WDEC + (size_t)4 * H_ * H_ * 4;    // 2 slots
constexpr size_t WS_DECA = WS_ENCA + (size_t)2 * ESLOTH * 2;
constexpr size_t WS_STRM = WS_DECA + (size_t)2 * DSLOTH * 2;
// strm: 128 wg * 2 kb * 32 kt * 2 nt * 64 lanes * 8 halfs = 8388608 halfs

// LDS byte offsets (fixed across roles)
constexpr int DBUF_B = 135168;           // f32[2][32][68]
constexpr int TBUF_B = DBUF_B + 17408;   // f32[8][64]
constexpr int ZP_B   = TBUF_B + 2048;    // 16 halfs of zeros
constexpr int LDS_B  = ZP_B + 64;
}

__device__ __forceinline__ f4 MF(h8 a, h8 b, f4 c) {
  return __builtin_amdgcn_mfma_f32_16x16x32_f16(a, b, c, 0, 0, 0);
}

// split v into fp16 hi (0 if would be denormal) + fp16 lo' scaled by 2048
__device__ __forceinline__ void fsplit(float v, f16& hi, f16& lo) {
  const float hf = (fabsf(v) >= 6.103515625e-05f) ? (float)(f16)v : 0.f;
  hi = (f16)hf;
  lo = (f16)((v - hf) * SC);
}

// ---- grid barrier: flag-array + master scan (no RMW serialization).
// arrival: release-store to private flag line (wb attached).  master (WG 255):
// 256 threads spin relaxed on one flag each, then tid0 release-stores gen.
// waiters: poll gen relaxed + one acquire load (invalidate) — R3 semantics. ----
__device__ __forceinline__ void gbar(unsigned* bar, int wg, unsigned& phase) {
  __syncthreads();
  ++phase;
  const int tid = threadIdx.x;
  unsigned* gen = bar + 8192;
  if (wg == MASTER) {
    if (tid == 0)
      __hip_atomic_store(&bar[MASTER * 32], phase, __ATOMIC_RELEASE, __HIP_MEMORY_SCOPE_AGENT);
    if (tid < 256) {
      while (__hip_atomic_load(&bar[tid * 32], __ATOMIC_RELAXED, __HIP_MEMORY_SCOPE_AGENT) < phase)
        __builtin_amdgcn_s_sleep(1);
    }
    __syncthreads();
    if (tid == 0) {
      __hip_atomic_store(gen, phase, __ATOMIC_RELEASE, __HIP_MEMORY_SCOPE_AGENT);
      (void)__hip_atomic_load(gen, __ATOMIC_ACQUIRE, __HIP_MEMORY_SCOPE_AGENT);
    }
  } else {
    if (tid == 0) {
      __hip_atomic_store(&bar[wg * 32], phase, __ATOMIC_RELEASE, __HIP_MEMORY_SCOPE_AGENT);
      while (__hip_atomic_load(gen, __ATOMIC_RELAXED, __HIP_MEMORY_SCOPE_AGENT) < phase)
        __builtin_amdgcn_s_sleep(1);
      (void)__hip_atomic_load(gen, __ATOMIC_ACQUIRE, __HIP_MEMORY_SCOPE_AGENT);
    }
  }
  __syncthreads();
}

// ---- staging: f32 weights -> fp16 hi/lo pairs in LDS ----
// encoder packed 24-slot rows (pad to 25): slots 0..15 = r,z ; 16..23 = ni(x-side)/nh(h-side)
__device__ void stageEnc(f16* __restrict__ whi, f16* __restrict__ wlo,
                         const float* __restrict__ Wx, const float* __restrict__ Wh,
                         int KX, int XOo, int KO, int u0, int tid) {
  for (int task = tid; task < KO * 24; task += NTH) {
    const int oct = task / 24;
    const int sl = task - oct * 24;
    const int g = (sl < 16) ? (sl >> 3) : 2;
    const int u = u0 + (sl & 7);
    const float* src = (oct < XOo)
        ? (Wx + (size_t)(g * H_ + u) * KX + (size_t)oct * 8)
        : (Wh + (size_t)(g * H_ + u) * H_ + (size_t)(oct - XOo) * 8);
    const float4 a = *(const float4*)src;
    const float4 b = *(const float4*)(src + 4);
    const float v[8] = {a.x, a.y, a.z, a.w, b.x, b.y, b.z, b.w};
    h8 hv, lv;
#pragma unroll
    for (int e = 0; e < 8; ++e) { f16 hh, ll; fsplit(v[e], hh, ll); hv[e] = hh; lv[e] = ll; }
    *(h8*)(whi + ((size_t)oct * 25 + sl) * 8) = hv;
    if (wlo) *(h8*)(wlo + ((size_t)oct * 25 + sl) * 8) = lv;
  }
}

// decoder 32-slot rows (pad 33): slots g*8+j, g in {r,z,ni,nh}, full K
__device__ void stageDec(f16* __restrict__ whi, f16* __restrict__ wlo,
                         const float* __restrict__ wdec, const float* __restrict__ dWhh,
                         int u0, int tid, bool t1set) {
  for (int task = tid; task < 128 * 32; task += NTH) {
    const int oct = task >> 5, sl = task & 31;
    const int g = sl >> 3;
    const int u = u0 + (sl & 7);
    float v[8];
    if (t1set) {
      if (g == 2) {
#pragma unroll
        for (int e = 0; e < 8; ++e) v[e] = 0.f;
      } else {
        const float* s = dWhh + (size_t)((g == 3 ? 2 : g) * H_ + u) * H_ + (size_t)oct * 8;
        const float4 a = *(const float4*)s, b = *(const float4*)(s + 4);
        v[0]=a.x; v[1]=a.y; v[2]=a.z; v[3]=a.w; v[4]=b.x; v[5]=b.y; v[6]=b.z; v[7]=b.w;
      }
    } else {
      const float* s = wdec + (size_t)(g * H_ + u) * H_ + (size_t)oct * 8;
      const float4 a = *(const float4*)s, b = *(const float4*)(s + 4);
      v[0]=a.x; v[1]=a.y; v[2]=a.z; v[3]=a.w; v[4]=b.x; v[5]=b.y; v[6]=b.z; v[7]=b.w;
    }
    h8 hv, lv;
#pragma unroll
    for (int e = 0; e < 8; ++e) { f16 hh, ll; fsplit(v[e], hh, ll); hv[e] = hh; lv[e] = ll; }
    *(h8*)(whi + ((size_t)oct * 33 + sl) * 8) = hv;
    *(h8*)(wlo + ((size_t)oct * 33 + sl) * 8) = lv;
  }
}

__device__ void stageProj(f16* __restrict__ whi, f16* __restrict__ wlo,
                          const float* __restrict__ pW, int f0, int tid) {
  for (int task = tid; task < 128 * 16; task += NTH) {
    const int oct = task >> 4, sl = task & 15;
    const float* s = pW + (size_t)(f0 + sl) * H_ + (size_t)oct * 8;
    const float4 a = *(const float4*)s, b = *(const float4*)(s + 4);
    const float v[8] = {a.x, a.y, a.z, a.w, b.x, b.y, b.z, b.w};
    h8 hv, lv;
#pragma unroll
    for (int e = 0; e < 8; ++e) { f16 hh, ll; fsplit(v[e], hh, ll); hv[e] = hh; lv[e] = ll; }
    *(h8*)(whi + ((size_t)oct * 17 + sl) * 8) = hv;
    *(h8*)(wlo + ((size_t)oct * 17 + sl) * 8) = lv;
  }
}

// ---- MFMA k-phase: A (hi+lo pairs) from global state, Whi from LDS, Wlo from
// LDS or stream.  1-deep software pipeline (shallow in-flight depth preserves
// L1/L2 locality — deeper pipelining measured worse, R8/R9/R10/R13). ----
template<int NT, bool NSPLIT, int ROWH, bool STRM>
__device__ __forceinline__ void gmm(f4* Dh, f4* Dc,
    const f16* __restrict__ Ab, int aoctBase, int loOct,
    const f16* __restrict__ whi, const f16* __restrict__ wlo,
    const f16* __restrict__ strm,
    int ktn, int octBase, int XO, int ls, int lq, int lane,
    const f16* __restrict__ zp) {
  auto LD = [&](int kk, h8& ah, h8& al, h8& bh0, h8& bl0, h8& bh1, h8& bl1) {
    const int aoct = aoctBase + kk * 4 + lq;
    ah = *(const h8*)(Ab + (size_t)aoct * 512);
    al = *(const h8*)(Ab + (size_t)(aoct + loOct) * 512);
    const int oct = octBase + kk * 4 + lq;
    bh0 = *(const h8*)(whi + ((size_t)oct * ROWH + ls) * 8);
    if constexpr (STRM) bl0 = *(const h8*)(strm + ((size_t)(kk * 2) * 64 + lane) * 8);
    else bl0 = *(const h8*)(wlo + ((size_t)oct * ROWH + ls) * 8);
    if constexpr (NT == 2) {
      bool act = true; int psl;
      if constexpr (NSPLIT) { act = (ls < 8) ? (oct < XO) : (oct >= XO); psl = 16 + (ls & 7); }
      else { psl = 16 + ls; }
      bh1 = *(const h8*)(act ? (whi + ((size_t)oct * ROWH + psl) * 8) : zp);
      if constexpr (STRM) bl1 = *(const h8*)(strm + ((size_t)(kk * 2 + 1) * 64 + lane) * 8);
      else bl1 = *(const h8*)(act ? (wlo + ((size_t)oct * ROWH + psl) * 8) : zp);
    }
  };
  h8 ah, al, bh0, bl0, bh1, bl1;
  LD(0, ah, al, bh0, bl0, bh1, bl1);
  for (int kk = 0; kk < ktn; ++kk) {
    h8 ah2, al2, bh02, bl02, bh12, bl12;
    const int nk = (kk + 1 < ktn) ? (kk + 1) : kk;
    LD(nk, ah2, al2, bh02, bl02, bh12, bl12);
    Dh[0] = MF(ah, bh0, Dh[0]);
    Dc[0] = MF(al, bh0, Dc[0]);
    Dc[0] = MF(ah, bl0, Dc[0]);
    if constexpr (NT == 2) {
      Dh[1] = MF(ah, bh1, Dh[1]);
      Dc[1] = MF(al, bh1, Dc[1]);
      Dc[1] = MF(ah, bl1, Dc[1]);
    }
    ah = ah2; al = al2; bh0 = bh02; bl0 = bl02;
    if constexpr (NT == 2) { bh1 = bh12; bl1 = bl12; }
  }
}

// encoder L0 x-part: f32 x -> in-register hi/lo, W octs 0..19 (ni active, nh inactive)
__device__ __forceinline__ void gmm_x(f4* Dh, f4* Dc, const float* __restrict__ xp,
    const f16* __restrict__ whi, const f16* __restrict__ wlo,
    int ls, int lq, const f16* __restrict__ zp) {
#pragma unroll
  for (int kk = 0; kk < 5; ++kk) {
    const float4 a = *(const float4*)(xp + kk * 32);
    const float4 b = *(const float4*)(xp + kk * 32 + 4);
    const float v[8] = {a.x, a.y, a.z, a.w, b.x, b.y, b.z, b.w};
    h8 ah, al;
#pragma unroll
    for (int e = 0; e < 8; ++e) { f16 hh, ll; fsplit(v[e], hh, ll); ah[e] = hh; al[e] = ll; }
    const int oct = kk * 4 + lq;
    {
      const h8 bh2 = *(const h8*)(whi + ((size_t)oct * 25 + ls) * 8);
      const h8 bl2 = *(const h8*)(wlo + ((size_t)oct * 25 + ls) * 8);
      Dh[0] = MF(ah, bh2, Dh[0]);
      Dc[0] = MF(al, bh2, Dc[0]);
      Dc[0] = MF(ah, bl2, Dc[0]);
    }
    {
      const bool act = (ls < 8);
      const int psl = 16 + (ls & 7);
      const h8 bh2 = *(const h8*)(act ? (whi + ((size_t)oct * 25 + psl) * 8) : zp);
      const h8 bl2 = *(const h8*)(act ? (wlo + ((size_t)oct * 25 + psl) * 8) : zp);
      Dh[1] = MF(ah, bh2, Dh[1]);
      Dc[1] = MF(al, bh2, Dc[1]);
      Dc[1] = MF(ah, bl2, Dc[1]);
    }
  }
}

// ---- setup kernels ----
__global__ void build_c_kernel(const float* __restrict__ dWih, const float* __restrict__ dbih,
                               const float* __restrict__ pb, float* __restrict__ cvec) {
  const int r = blockIdx.x * 256 + threadIdx.x;
  if (r >= 3 * H_) return;
  float a = dbih[r];
  for (int f = 0; f < F_; ++f) a += dWih[(size_t)r * F_ + f] * pb[f];
  cvec[r] = a;
}

// wdec rows [0,3H): (dWih@pW) (+dWhh for r,z). one thread = (row, oct of 8 k)
__global__ void build_wdec_kernel(const float* __restrict__ dWih, const float* __restrict__ dWhh,
                                  const float* __restrict__ pW, float* __restrict__ wdec) {
  const int idx = blockIdx.x * 256 + threadIdx.x;
  if (idx >= 3 * H_ * 128) return;
  const int row = idx >> 7;
  const int oct = idx & 127;
  float v[8] = {0, 0, 0, 0, 0, 0, 0, 0};
  const float* wr = dWih + (size_t)row * F_;
  for (int f = 0; f < F_; ++f) {
    const float w = wr[f];
    const float4 p0 = *(const float4*)(pW + (size_t)f * H_ + oct * 8);
    const float4 p1 = *(const float4*)(pW + (size_t)f * H_ + oct * 8 + 4);
    v[0] += w * p0.x; v[1] += w * p0.y; v[2] += w * p0.z; v[3] += w * p0.w;
    v[4] += w * p1.x; v[5] += w * p1.y; v[6] += w * p1.z; v[7] += w * p1.w;
  }
  if ((row >> 10) < 2) {
    const float* hr = dWhh + (size_t)row * H_ + oct * 8;
#pragma unroll
    for (int e = 0; e < 8; ++e) v[e] += hr[e];
  }
  float* o = wdec + (size_t)row * H_ + oct * 8;
#pragma unroll
  for (int e = 0; e < 8; ++e) o[e] = v[e];
}
__global__ void build_wdec_nh(const float* __restrict__ dWhh, float* __restrict__ wdec) {
  const int idx = blockIdx.x * 256 + threadIdx.x;
  if (idx >= H_ * H_) return;
  wdec[(size_t)3 * H_ * H_ + idx] = dWhh[(size_t)2 * H_ * H_ + idx];
}

// L1 lo-fragment stream, fragment-ordered: [(wg*2+kb)*32768 + ((kk*2+nt)*64+lane)*8 + j]
__global__ void build_strm(const float* __restrict__ Wih1, const float* __restrict__ Whh1,
                           f16* __restrict__ strm) {
  const size_t idx = (size_t)blockIdx.x * 256 + threadIdx.x;  // 8388608 total
  const int j = (int)(idx & 7);
  const int lane = (int)((idx >> 3) & 63);
  const int nt = (int)((idx >> 9) & 1);
  const int kk = (int)((idx >> 10) & 31);
  const int kb = (int)((idx >> 15) & 1);
  const int wg = (int)(idx >> 16);
  const int c = lane & 15, lq = lane >> 4;
  const int oct = kb * 128 + kk * 4 + lq;
  const int k = oct * 8 + j;
  float v = 0.f;
  if (nt == 0) {
    const int row = (c >> 3) * H_ + wg * 8 + (c & 7);
    v = (oct < 128) ? Wih1[(size_t)row * H_ + k] : Whh1[(size_t)row * H_ + (k - 1024)];
  } else {
    const bool act = (c < 8) ? (oct < 128) : (oct >= 128);
    if (act) {
      const int row = 2 * H_ + wg * 8 + (c & 7);
      v = (oct < 128) ? Wih1[(size_t)row * H_ + k] : Whh1[(size_t)row * H_ + (k - 1024)];
    }
  }
  f16 hh, ll; fsplit(v, hh, ll);
  strm[idx] = ll;
}

// ---- persistent kernel ----
__global__ void __launch_bounds__(NTH, 1) speech_ae_persistent(
    const float* __restrict__ x,
    const float* __restrict__ Wih0, const float* __restrict__ Whh0,
    const float* __restrict__ bih0, const float* __restrict__ bhh0,
    const float* __restrict__ Wih1, const float* __restrict__ Whh1,
    const float* __restrict__ bih1, const float* __restrict__ bhh1,
    const float* __restrict__ fcW, const float* __restrict__ fcb,
    const float* __restrict__ dbih, const float* __restrict__ dbhh,
    const float* __restrict__ pW, const float* __restrict__ pb,
    const float* __restrict__ dWhh,
    float* __restrict__ out, void* ws) {
  extern __shared__ char ldsb[];
  f16* wh = (f16*)ldsb;
  float* dbuf = (float*)(ldsb + DBUF_B);
  float* tbuf = (float*)(ldsb + TBUF_B);
  f16* zp = (f16*)(ldsb + ZP_B);

  char* wsb = (char*)ws;
  unsigned* bar = (unsigned*)(wsb + WS_BAR);
  const float* cvec = (const float*)(wsb + WS_CVEC);
  const float* wdec = (const float*)(wsb + WS_WDEC);
  f16* encA = (f16*)(wsb + WS_ENCA);
  f16* decA = (f16*)(wsb + WS_DECA);
  const f16* strm = (const f16*)(wsb + WS_STRM);

  const int tid = threadIdx.x, wg = blockIdx.x;
  const int lane = tid & 63, wv = tid >> 6;
  const int ls = lane & 15, lq = lane >> 4;
  const int m0 = (wv & 3) * 16, kb = wv >> 2;
  const int mb = m0 + ls;
  const bool isL1 = (wg < 128);
  unsigned phase = 0;
  const f16* strmW = strm + (size_t)(wg * 2 + kb) * 32768;

  // encoder biases (8 units/WG; thread's unit = wv)
  const float* bi = isL1 ? bih1 : bih0;
  const float* bh_ = isL1 ? bhh1 : bhh0;
  const int eru = (isL1 ? wg * 8 : (wg - 128) * 8) + wv;
  const float ebr = bi[eru] + bh_[eru];
  const float ebz = bi[H_ + eru] + bh_[H_ + eru];
  const float ebni = bi[2 * H_ + eru];
  const float ebnh = bh_[2 * H_ + eru];
  float hreg = 0.f;

  // decoder biases
  float b1r = 0, b1z = 0, b1ni = 0, b1nh = 0, bfr = 0, bfz = 0, bfni = 0, bfnh = 0, hdreg = 0.f;
  if (wg < 128) {
    const int rw = wg * 8 + wv;
    b1r = dbih[rw] + dbhh[rw];
    b1z = dbih[H_ + rw] + dbhh[H_ + rw];
    b1ni = dbih[2 * H_ + rw];
    b1nh = dbhh[2 * H_ + rw];
    bfr = cvec[rw] + dbhh[rw];
    bfz = cvec[H_ + rw] + dbhh[H_ + rw];
    bfni = cvec[2 * H_ + rw];
    bfnh = dbhh[2 * H_ + rw];
  }
  const int f0 = (wg - 128) * 16;
  float pbr[4] = {0, 0, 0, 0};
  if (wg >= 128 && wg < 138 && tid < 256) {
    const int fq = tid & 3;
#pragma unroll
    for (int e = 0; e < 4; ++e) pbr[e] = pb[f0 + fq * 4 + e];
  }

  // stage encoder weights
  if (isL1) stageEnc(wh, nullptr, Wih1, Whh1, H_, 128, 256, wg * 8, tid);
  else stageEnc(wh, wh + 29600, Wih0, Whh0, F_, 20, 148, (wg - 128) * 8, tid);
  if (tid < 16) zp[tid] = (f16)0.f;
  __syncthreads();

  // ============ encoder: L0 (wg>=128) at t=s, L1 (wg<128) at t=s-1 ============
  for (int s = 0; s <= T_; ++s) {
    const bool active = isL1 ? (s >= 1) : (s < T_);
    if (active) {
      const int t = isL1 ? (s - 1) : s;
      f4 Dh[2] = {{0.f,0.f,0.f,0.f},{0.f,0.f,0.f,0.f}};
      f4 Dc[2] = {{0.f,0.f,0.f,0.f},{0.f,0.f,0.f,0.f}};
      if (isL1) {
        if (kb == 0) {        // h0_t part, W octs 0..127
          const f16* Ab = encA + (size_t)(t & 1) * ESLOTH + (size_t)mb * 8;
          gmm<2, true, 25, true>(Dh, Dc, Ab, 0, ELO, wh, nullptr, strmW, 32, 0, 128, ls, lq, lane, zp);
        } else if (t >= 1) {  // h1_{t-1} part, W octs 128..255
          const f16* Ab = encA + (size_t)((t - 1) & 1) * ESLOTH + (size_t)mb * 8;
          gmm<2, true, 25, true>(Dh, Dc, Ab, 128, ELO, wh, nullptr, strmW, 32, 128, 128, ls, lq, lane, zp);
        }
      } else {
        if (kb == 0) {
          const float* xp = x + ((size_t)mb * T_ + t) * F_ + lq * 8;
          gmm_x(Dh, Dc, xp, wh, wh + 29600, ls, lq, zp);
          if (t >= 1) {
            const f16* Ab = encA + (size_t)((t - 1) & 1) * ESLOTH + (size_t)mb * 8;
            gmm<2, true, 25, false>(Dh, Dc, Ab, 0, ELO, wh, wh + 29600, nullptr, 14, 20, 20, ls, lq, lane, zp);
          }
        } else if (t >= 1) {
          const f16* Ab = encA + (size_t)((t - 1) & 1) * ESLOTH + (size_t)mb * 8;
          gmm<2, true, 25, false>(Dh, Dc, Ab, 56, ELO, wh, wh + 29600, nullptr, 18, 76, 20, ls, lq, lane, zp);
        }
      }
      *(f4*)(dbuf + kb * 2176 + ls * 68 + m0 + lq * 4) = Dh[0] + Dc[0] * INV;
      *(f4*)(dbuf + kb * 2176 + (16 + ls) * 68 + m0 + lq * 4) = Dh[1] + Dc[1] * INV;
      __syncthreads();
      const int b = lane;
      const float gr  = dbuf[wv * 68 + b]        + dbuf[2176 + wv * 68 + b]        + ebr;
      const float gz  = dbuf[(8 + wv) * 68 + b]  + dbuf[2176 + (8 + wv) * 68 + b]  + ebz;
      const float gni = dbuf[(16 + wv) * 68 + b] + dbuf[2176 + (16 + wv) * 68 + b] + ebni;
      const float gnh = dbuf[(24 + wv) * 68 + b] + dbuf[2176 + (24 + wv) * 68 + b] + ebnh;
      const float rg = 1.f / (1.f + expf(-gr));
      const float zg = 1.f / (1.f + expf(-gz));
      const float ng = tanhf(gni + rg * gnh);
      const float hn = (1.f - zg) * ng + zg * hreg;
      hreg = hn;
      tbuf[wv * 64 + b] = hn;
      __syncthreads();
      if (tid < 64) {
        const int oct = isL1 ? (128 + wg) : (wg - 128);
        f16* dst = encA + (size_t)(t & 1) * ESLOTH + ((size_t)oct * 64 + tid) * 8;
        h8 hv, lv;
#pragma unroll
        for (int e = 0; e < 8; ++e) { f16 hh, ll; fsplit(tbuf[e * 64 + tid], hh, ll); hv[e] = hh; lv[e] = ll; }
        *(h8*)dst = hv;
        *(h8*)(dst + (size_t)ELO * 512) = lv;
      }
    }
    gbar(bar, wg, phase);
  }

  // ============ fc -> hd0 (wg<128) ============
  if (wg < 128) {
    const int u0f = wg * 8;
    const int b = lane;
    float acc[8] = {0, 0, 0, 0, 0, 0, 0, 0};
    for (int ko = wv * 32; ko < wv * 32 + 32; ++ko) {
      const f16* hp = encA + ESLOTH + ((size_t)ko * 64 + b) * 8;
      const h8 hiv = *(const h8*)hp;
      const h8 lov = *(const h8*)(hp + (size_t)ELO * 512);
      float hv[8];
#pragma unroll
      for (int e = 0; e < 8; ++e) hv[e] = (float)hiv[e] + (float)lov[e] * INV;
#pragma unroll
      for (int u = 0; u < 8; ++u) {
        const float* wr = fcW + (size_t)(u0f + u) * 2048 + (size_t)ko * 8;
        const float4 wa = *(const float4*)wr, wb = *(const float4*)(wr + 4);
        acc[u] += hv[0] * wa.x + hv[1] * wa.y + hv[2] * wa.z + hv[3] * wa.w
                + hv[4] * wb.x + hv[5] * wb.y + hv[6] * wb.z + hv[7] * wb.w;
      }
    }
    __syncthreads();
#pragma unroll
    for (int u = 0; u < 8; ++u) dbuf[(u * 8 + wv) * 68 + b] = acc[u];
    __syncthreads();
    float sum = fcb[u0f + wv];
#pragma unroll
    for (int g = 0; g < 8; ++g) sum += dbuf[(wv * 8 + g) * 68 + lane];
    tbuf[wv * 64 + lane] = tanhf(sum);
    __syncthreads();
    if (tid < 64) {
      f16* dst = decA + ((size_t)wg * 64 + tid) * 8;   // slot0, oct = wg
      h8 hv, lv;
#pragma unroll
      for (int e = 0; e < 8; ++e) { f16 hh, ll; fsplit(tbuf[e * 64 + tid], hh, ll); hv[e] = hh; lv[e] = ll; }
      *(h8*)dst = hv;
      *(h8*)(dst + (size_t)DLO * 512) = lv;
    }
  }
  // stage decoder t=1 weights / proj weights
  if (wg < 128) stageDec(wh, wh + 33792, nullptr, dWhh, wg * 8, tid, true);
  else if (wg < 138) stageProj(wh, wh + 17408, pW, f0, tid);
  gbar(bar, wg, phase);   // publish decA slot0

  // decoder GRU step; hprev for t=1 from tbuf (fc output still resident in LDS)
  auto dec_step = [&](int t, bool first) {
    f4 Dh[2] = {{0.f,0.f,0.f,0.f},{0.f,0.f,0.f,0.f}};
    f4 Dc[2] = {{0.f,0.f,0.f,0.f},{0.f,0.f,0.f,0.f}};
    const f16* Ab = decA + (size_t)((t - 1) & 1) * DSLOTH + (size_t)mb * 8;
    gmm<2, false, 33, false>(Dh, Dc, Ab, kb * 64, DLO, wh, wh + 33792, nullptr, 16, kb * 64, 0, ls, lq, lane, zp);
    *(f4*)(dbuf + kb * 2176 + ls * 68 + m0 + lq * 4) = Dh[0] + Dc[0] * INV;
    *(f4*)(dbuf + kb * 2176 + (16 + ls) * 68 + m0 + lq * 4) = Dh[1] + Dc[1] * INV;
    __syncthreads();
    const int b = lane;
    const float hprev = first ? tbuf[wv * 64 + b] : hdreg;
    const float gr  = dbuf[wv * 68 + b]        + dbuf[2176 + wv * 68 + b]        + (first ? b1r : bfr);
    const float gz  = dbuf[(8 + wv) * 68 + b]  + dbuf[2176 + (8 + wv) * 68 + b]  + (first ? b1z : bfz);
    const float gni = dbuf[(16 + wv) * 68 + b] + dbuf[2176 + (16 + wv) * 68 + b] + (first ? b1ni : bfni);
    const float gnh = dbuf[(24 + wv) * 68 + b] + dbuf[2176 + (24 + wv) * 68 + b] + (first ? b1nh : bfnh);
    const float rg = 1.f / (1.f + expf(-gr));
    const float zg = 1.f / (1.f + expf(-gz));
    const float ng = tanhf(gni + rg * gnh);
    const float hn = (1.f - zg) * ng + zg * hprev;
    hdreg = hn;
    tbuf[wv * 64 + b] = hn;
    __syncthreads();
    if (tid < 64) {
      f16* dst = decA + (size_t)(t & 1) * DSLOTH + ((size_t)wg * 64 + tid) * 8;
      h8 hv, lv;
#pragma unroll
      for (int e = 0; e < 8; ++e) { f16 hh, ll; fsplit(tbuf[e * 64 + tid], hh, ll); hv[e] = hh; lv[e] = ll; }
      *(h8*)dst = hv;
      *(h8*)(dst + (size_t)DLO * 512) = lv;
    }
  };

  auto proj = [&](int t2) {
    f4 Dh[1] = {{0.f,0.f,0.f,0.f}};
    f4 Dc[1] = {{0.f,0.f,0.f,0.f}};
    const f16* Ab = decA + (size_t)((t2 - 1) & 1) * DSLOTH + (size_t)mb * 8;
    gmm<1, false, 17, false>(Dh, Dc, Ab, kb * 64, DLO, wh, wh + 17408, nullptr, 16, kb * 64, 0, ls, lq, lane, zp);
    *(f4*)(dbuf + kb * 2176 + ls * 68 + m0 + lq * 4) = Dh[0] + Dc[0] * INV;
    __syncthreads();
    if (tid < 256) {
      const int b2 = tid >> 2, fq = tid & 3;
      float4 o;
      o.x = dbuf[(fq * 4 + 0) * 68 + b2] + dbuf[2176 + (fq * 4 + 0) * 68 + b2] + pbr[0];
      o.y = dbuf[(fq * 4 + 1) * 68 + b2] + dbuf[2176 + (fq * 4 + 1) * 68 + b2] + pbr[1];
      o.z = dbuf[(fq * 4 + 2) * 68 + b2] + dbuf[2176 + (fq * 4 + 2) * 68 + b2] + pbr[2];
      o.w = dbuf[(fq * 4 + 3) * 68 + b2] + dbuf[2176 + (fq * 4 + 3) * 68 + b2] + pbr[3];
      *(float4*)(out + (size_t)b2 * (T_ * F_) + (size_t)(t2 - 2) * F_ + f0 + fq * 4) = o;
    }
  };

  // t = 1 (dWhh set), then swap in fused weights (LDS-local, no extra barrier)
  if (wg < 128) dec_step(1, true);
  gbar(bar, wg, phase);   // publish hd_1
  if (wg < 128) {
    stageDec(wh, wh + 33792, wdec, nullptr, wg * 8, tid, false);
    __syncthreads();
  }

  // ============ decoder main loop ============
  for (int t2 = 2; t2 <= T_ + 1; ++t2) {
    if (wg < 128) {
      if (t2 <= T_) dec_step(t2, false);
    } else if (wg < 138) {
      proj(t2);
    }
    gbar(bar, wg, phase);
  }
}

extern "C" void kernel_launch(void* const* d_in, const int* in_sizes, int n_in,
                              void* d_out, int out_size, void* d_ws, size_t ws_size,
                              hipStream_t stream) {
  (void)in_sizes; (void)n_in; (void)out_size; (void)ws_size;
  const float* x    = (const float*)d_in[0];
  const float* Wih0 = (const float*)d_in[1];
  const float* Whh0 = (const float*)d_in[2];
  const float* bih0 = (const float*)d_in[3];
  const float* bhh0 = (const float*)d_in[4];
  const float* Wih1 = (const float*)d_in[5];
  const float* Whh1 = (const float*)d_in[6];
  const float* bih1 = (const float*)d_in[7];
  const float* bhh1 = (const float*)d_in[8];
  const float* fcW  = (const float*)d_in[9];
  const float* fcb  = (const float*)d_in[10];
  const float* dWih = (const float*)d_in[11];
  const float* dWhh = (const float*)d_in[12];
  const float* dbih = (const float*)d_in[13];
  const float* dbhh = (const float*)d_in[14];
  const float* pW   = (const float*)d_in[15];
  const float* pb   = (const float*)d_in[16];
  float* out = (float*)d_out;
  char* wsb = (char*)d_ws;

  hipFuncSetAttribute((const void*)speech_ae_persistent,
                      hipFuncAttributeMaxDynamicSharedMemorySize, LDS_B);
  hipMemsetAsync(d_ws, 0, 32896, stream);
  build_c_kernel<<<(3 * H_ + 255) / 256, 256, 0, stream>>>(dWih, dbih, pb, (float*)(wsb + WS_CVEC));
  build_wdec_kernel<<<(3 * H_ * 128 + 255) / 256, 256, 0, stream>>>(dWih, dWhh, pW, (float*)(wsb + WS_WDEC));
  build_wdec_nh<<<(H_ * H_ + 255) / 256, 256, 0, stream>>>(dWhh, (float*)(wsb + WS_WDEC));
  build_strm<<<32768, 256, 0, stream>>>(Wih1, Whh1, (f16*)(wsb + WS_STRM));
  speech_ae_persistent<<<NWG, NTH, LDS_B, stream>>>(
      x, Wih0, Whh0, bih0, bhh0, Wih1, Whh1, bih1, bhh1, fcW, fcb,
      dbih, dbhh, pW, pb, dWhh, out, d_ws);
}